// Round 1
// 313.194 us; speedup vs baseline: 1.0460x; 1.0460x over previous
//
#include <hip/hip_runtime.h>

#define HBLK 128  // hidden width, fixed by problem

typedef __attribute__((ext_vector_type(8))) short s8v;    // 8 bf16 in 4 VGPRs
typedef __attribute__((ext_vector_type(4))) float f32x4;  // MFMA accumulator
typedef __attribute__((ext_vector_type(8))) _Float16 h8f; // 8 fp16 = 16B

// split fp32 into bf16 hi + lo (truncation; residual <= 2^-16 |x|)
__device__ inline void split2(float x, short& h, short& l) {
    unsigned hb = __float_as_uint(x) & 0xFFFF0000u;
    float hf = __uint_as_float(hb);
    float lf = x - hf;
    h = (short)(hb >> 16);
    l = (short)(__float_as_uint(lf) >> 16);
}

__device__ inline void split8(const float4& a0, const float4& a1, s8v& ah, s8v& al) {
    float vv[8];
    *(float4*)&vv[0] = a0;
    *(float4*)&vv[4] = a1;
#pragma unroll
    for (int e = 0; e < 8; ++e) {
        short hh, ll;
        split2(vv[e], hh, ll);
        ah[e] = hh;
        al[e] = ll;
    }
}

// ---------------- CSR build ----------------
__global__ void zero_counts(int* counts, int n) {
    int i = blockIdx.x * 256 + threadIdx.x;
    if (i < n) counts[i] = 0;
}

__global__ void hist_k(const int* __restrict__ dst, int* counts, int E) {
    int e = blockIdx.x * 256 + threadIdx.x;
    if (e < E) atomicAdd(&counts[dst[e]], 1);
}

// ---- parallel exclusive scan, 3 phases (N up to 256*256) ----
__global__ void scan1(const int* __restrict__ counts, int* __restrict__ offs,
                      int* __restrict__ bsums, int n) {
    __shared__ int lds[256];
    const int t = threadIdx.x;
    const int i = blockIdx.x * 256 + t;
    const int v = (i < n) ? counts[i] : 0;
    lds[t] = v;
    __syncthreads();
    for (int off = 1; off < 256; off <<= 1) {
        int add = (t >= off) ? lds[t - off] : 0;
        __syncthreads();
        lds[t] += add;
        __syncthreads();
    }
    if (i < n) offs[i] = lds[t] - v;          // exclusive within block
    if (t == 255) bsums[blockIdx.x] = lds[255];
}

__global__ void scan2(int* __restrict__ bsums, int nb) {
    __shared__ int lds[256];
    const int t = threadIdx.x;
    const int v = (t < nb) ? bsums[t] : 0;
    lds[t] = v;
    __syncthreads();
    for (int off = 1; off < 256; off <<= 1) {
        int add = (t >= off) ? lds[t - off] : 0;
        __syncthreads();
        lds[t] += add;
        __syncthreads();
    }
    if (t < nb) bsums[t] = lds[t] - v;        // exclusive block prefix
}

__global__ void scan3(int* __restrict__ offs, int* __restrict__ cursor,
                      const int* __restrict__ bsums, int n, int E) {
    const int i = blockIdx.x * 256 + threadIdx.x;
    if (i < n) {
        int v = offs[i] + bsums[blockIdx.x];
        offs[i] = v;
        cursor[i] = v;
    }
    if (i == 0) offs[n] = E;                  // total: every edge has a dst
}

// single scattered store carrying the payload: src_sorted[p] = src[e]
__global__ void fill_k(const int* __restrict__ dst, const int* __restrict__ src,
                       int* cursor, int* __restrict__ src_sorted, int E) {
    int e = blockIdx.x * 256 + threadIdx.x;
    if (e < E) {
        int p = atomicAdd(&cursor[dst[e]], 1);
        if (p >= 0 && p < E) src_sorted[p] = src[e];
    }
}

// ---------------- algebraic fold: W_comb = W_cat[:,MAPD:] @ W_eh ----------------
// hin = relu([maps|feats@Weh^T+beh] @ Wcat^T + bcat)
//     = relu(maps @ Wc1^T + feats @ Wcomb^T + bcomb)
// Wcomb[c][k] = sum_j Wcat[c][MAPD+j] * Weh[j][k];  bcomb[c] = bcat[c] + sum_j Wcat[c][MAPD+j]*beh[j]
__global__ void make_wcomb(const float* __restrict__ Wcat, int ldw, int mapd,
                           const float* __restrict__ Weh, int indim,
                           const float* __restrict__ beh, const float* __restrict__ bcat,
                           float* __restrict__ Wcomb, float* __restrict__ bcomb) {
    const int i = blockIdx.x * 256 + threadIdx.x;
    const int total = HBLK * indim;
    if (i < total) {
        const int c = i / indim, k = i % indim;
        const float* wc = Wcat + (long)c * ldw + mapd;
        float s = 0.f;
        for (int j = 0; j < HBLK; ++j) s += wc[j] * Weh[j * indim + k];
        Wcomb[(long)c * indim + k] = s;
    } else if (i < total + HBLK) {
        const int c = i - total;
        const float* wc = Wcat + (long)c * ldw + mapd;
        float s = bcat[c];
        for (int j = 0; j < HBLK; ++j) s += wc[j] * beh[j];
        bcomb[c] = s;
    }
}

// ---------------- weight split + pack into MFMA-fragment order ----------------
// Chunk-major: off = ((chunk*(C/16) + j)*64 + quad*16 + l16)*8 + t
__global__ void split_w_pack(const float* __restrict__ W, int ldw, int kin, int cin,
                             short* __restrict__ dh, short* __restrict__ dl,
                             int C, int K) {
    long i = (long)blockIdx.x * 256 + threadIdx.x;
    if (i >= (long)C * K) return;
    int c = (int)(i / K), k = (int)(i % K);
    float x = (k < kin && c < cin) ? W[(long)c * ldw + k] : 0.f;
    short h, l;
    split2(x, h, l);
    int nj = C >> 4;
    int j = c >> 4, l16 = c & 15;
    int chunk = k >> 5, quad = (k >> 3) & 3, t = k & 7;
    long off = (((long)(chunk * nj + j) * 64) + quad * 16 + l16) * 8 + t;
    dh[off] = h;
    dl[off] = l;
}

// combined concat weight: k<mapd from Wcat, mapd<=k<mapd+indim from Wcomb, pad 0
__global__ void pack_wcat(const float* __restrict__ Wcat, int ldw, int mapd,
                          const float* __restrict__ Wcomb, int indim,
                          short* __restrict__ dh, short* __restrict__ dl, int K) {
    long i = (long)blockIdx.x * 256 + threadIdx.x;
    if (i >= (long)HBLK * K) return;
    int c = (int)(i / K), k = (int)(i % K);
    float x = 0.f;
    if (k < mapd) x = Wcat[(long)c * ldw + k];
    else if (k < mapd + indim) x = Wcomb[(long)c * indim + (k - mapd)];
    short h, l;
    split2(x, h, l);
    int j = c >> 4, l16 = c & 15;
    int chunk = k >> 5, quad = (k >> 3) & 3, t = k & 7;
    long off = (((long)(chunk * 8 + j) * 64) + quad * 16 + l16) * 8 + t;
    dh[off] = h;
    dl[off] = l;
}

// all four 128x128 layer weights in one launch; matrix m at offset m*16384 shorts
__global__ void split_w_pack4(const float* __restrict__ W0, const float* __restrict__ W1,
                              const float* __restrict__ W2, const float* __restrict__ W3,
                              short* __restrict__ dh, short* __restrict__ dl) {
    const float* Ws[4] = {W0, W1, W2, W3};
    const int m = blockIdx.y;
    long i = (long)blockIdx.x * 256 + threadIdx.x;   // < 16384
    int c = (int)(i >> 7), k = (int)(i & 127);
    float x = Ws[m][c * HBLK + k];
    short h, l;
    split2(x, h, l);
    int j = c >> 4, l16 = c & 15;
    int chunk = k >> 5, quad = (k >> 3) & 3, t = k & 7;
    long off = (long)m * 16384 + (((long)(chunk * 8 + j) * 64) + quad * 16 + l16) * 8 + t;
    dh[off] = h;
    dl[off] = l;
}

// ---------------- big-K split-fp32 MFMA GEMM (concat): dual-A, LDS double-buffer ----------------
// Barrier is raw s_barrier + lgkmcnt(0) only: the private A-register prefetch
// (2 chunks deep) stays in flight across the barrier instead of being drained
// by __syncthreads' vmcnt(0). Always applies bias + relu.
__global__ __launch_bounds__(256, 2) void gemm_bigk(
    const float* __restrict__ A1, int lda1, int K1,
    const float* __restrict__ A2, int lda2, int Kin,
    int K,
    const short* __restrict__ Wh, const short* __restrict__ Wl,
    const float* __restrict__ bias,
    float* __restrict__ Cf, int M)
{
    __shared__ short lds_h[2][4096];   // 8 KB per buffer (one 32-k chunk, hi)
    __shared__ short lds_l[2][4096];
    const int tid = threadIdx.x;
    const int wv = tid >> 6;
    const int lane = tid & 63;
    const int l16 = lane & 15;
    const int quad = lane >> 4;
    const int m0 = blockIdx.x * 64 + wv * 16;
    int ra = m0 + l16;
    if (ra >= M) ra = M - 1;
    const long r1 = (long)ra * lda1;
    const long r2 = (long)ra * lda2;
    const int NC = K >> 5;

    f32x4 acc[8];
#pragma unroll
    for (int j = 0; j < 8; ++j) acc[j] = (f32x4){0.f, 0.f, 0.f, 0.f};

#define LOAD_A(d0, d1, kb)                                      \
    {                                                           \
        const int col0 = (kb) + quad * 8;                       \
        if (col0 < K1) {                                        \
            const float* ap = A1 + r1 + col0;                   \
            d0 = *(const float4*)ap;                            \
            d1 = *(const float4*)(ap + 4);                      \
        } else if (col0 < Kin) {                                \
            const float* ap = A2 + r2 + (col0 - K1);            \
            d0 = *(const float4*)ap;                            \
            d1 = *(const float4*)(ap + 4);                      \
        } else {                                                \
            d0 = make_float4(0.f, 0.f, 0.f, 0.f);               \
            d1 = make_float4(0.f, 0.f, 0.f, 0.f);               \
        }                                                       \
    }
#define LOAD_W(c)                                               \
    {                                                           \
        const int4* gh = (const int4*)(Wh + (long)(c) * 4096);  \
        const int4* gl = (const int4*)(Wl + (long)(c) * 4096);  \
        wh0 = gh[tid * 2]; wh1 = gh[tid * 2 + 1];               \
        wl0 = gl[tid * 2]; wl1 = gl[tid * 2 + 1];               \
    }
#define WRITE_W(b)                                              \
    {                                                           \
        int4* bh = (int4*)lds_h[b];                             \
        int4* bl = (int4*)lds_l[b];                             \
        bh[tid * 2] = wh0; bh[tid * 2 + 1] = wh1;               \
        bl[tid * 2] = wl0; bl[tid * 2 + 1] = wl1;               \
    }

    int4 wh0, wh1, wl0, wl1;
    LOAD_W(0)
    WRITE_W(0)
    LOAD_W(1)                               // chunk 1 held in regs until next stage point
    float4 a0c, a1c, a0n, a1n;
    float4 a0p = make_float4(0.f, 0.f, 0.f, 0.f);
    float4 a1p = make_float4(0.f, 0.f, 0.f, 0.f);
    LOAD_A(a0c, a1c, 0)
    LOAD_A(a0n, a1n, 32)
    asm volatile("s_waitcnt lgkmcnt(0)" ::: "memory");
    __builtin_amdgcn_s_barrier();
    asm volatile("" ::: "memory");

    for (int c = 0; c < NC; ++c) {
        const int nb = c & 1;
        // issue A prefetch for chunk c+2 (stays outstanding across the barrier)
        if (c + 2 < NC) {
            LOAD_A(a0p, a1p, (c + 2) * 32)
        }
        // compute chunk c from LDS buffer nb
        s8v ah, al;
        split8(a0c, a1c, ah, al);
#pragma unroll
        for (int j = 0; j < 8; ++j) {
            const s8v whf = *(const s8v*)&lds_h[nb][(j * 64 + lane) * 8];
            const s8v wlf = *(const s8v*)&lds_l[nb][(j * 64 + lane) * 8];
            acc[j] = __builtin_amdgcn_mfma_f32_16x16x32_bf16(ah, whf, acc[j], 0, 0, 0);
            acc[j] = __builtin_amdgcn_mfma_f32_16x16x32_bf16(ah, wlf, acc[j], 0, 0, 0);
            acc[j] = __builtin_amdgcn_mfma_f32_16x16x32_bf16(al, whf, acc[j], 0, 0, 0);
        }
        if (c + 1 < NC) {
            WRITE_W(nb ^ 1)                 // stage chunk c+1 (regs); waits only W loads
            if (c + 2 < NC) LOAD_W(c + 2)   // prefetch chunk c+2 into regs
            asm volatile("s_waitcnt lgkmcnt(0)" ::: "memory");
            __builtin_amdgcn_s_barrier();
            asm volatile("" ::: "memory");
        }
        a0c = a0n; a1c = a1n; a0n = a0p; a1n = a1p;
    }
#undef LOAD_A
#undef LOAD_W
#undef WRITE_W

    // C/D layout: col = lane&15, row = quad*4 + reg  (verified m89/m91)
#pragma unroll
    for (int r = 0; r < 4; ++r) {
        const int gr = m0 + quad * 4 + r;
        if (gr >= M) continue;
#pragma unroll
        for (int j = 0; j < 8; ++j) {
            const int col = j * 16 + l16;
            float v = acc[j][r] + bias[col];
            Cf[(long)gr * HBLK + col] = fmaxf(v, 0.f);
        }
    }
}

// ---------------- small-K (=128) dual GEMM: whole W staged once, zero loop barriers ----------------
// y==0: C1f = A @ W1^T (f32).  y==1: Czh = fp16(A @ W2^T) plus fused attention-score
// epilogue s_src/s_dst from avec.  64 KB LDS -> 2 blocks/CU.
__global__ __launch_bounds__(256, 2) void gemm_smallk(
    const float* __restrict__ A,
    const short* __restrict__ W1h, const short* __restrict__ W1l,
    const short* __restrict__ W2h, const short* __restrict__ W2l,
    float* __restrict__ C1f, _Float16* __restrict__ Czh,
    const float* __restrict__ avec,
    float* __restrict__ sOut, float* __restrict__ dOut, int M)
{
    __shared__ short lh[16384];   // 32 KB: full 128x128 hi
    __shared__ short ll[16384];   // 32 KB: full 128x128 lo
    const short* __restrict__ Wh = blockIdx.y ? W2h : W1h;
    const short* __restrict__ Wl = blockIdx.y ? W2l : W1l;
    float* __restrict__ Cf = blockIdx.y ? nullptr : C1f;
    _Float16* __restrict__ Ch16 = blockIdx.y ? Czh : nullptr;
    const float* __restrict__ av = blockIdx.y ? avec : nullptr;
    const int tid = threadIdx.x;
    const int wv = tid >> 6;
    const int lane = tid & 63;
    const int l16 = lane & 15;
    const int quad = lane >> 4;
    const int m0 = blockIdx.x * 64 + wv * 16;
    int ra = m0 + l16;
    if (ra >= M) ra = M - 1;
    const float* arow = A + (long)ra * HBLK + quad * 8;

    {   // stage whole weight: 2048 int4 per half, 8 per thread
        const int4* gh = (const int4*)Wh;
        const int4* gl = (const int4*)Wl;
        int4* bh = (int4*)lh;
        int4* bl = (int4*)ll;
#pragma unroll
        for (int i = 0; i < 8; ++i) {
            bh[i * 256 + tid] = gh[i * 256 + tid];
            bl[i * 256 + tid] = gl[i * 256 + tid];
        }
    }
    // issue all A loads up front (8 outstanding vmem)
    float4 aw0[4], aw1[4];
#pragma unroll
    for (int c = 0; c < 4; ++c) {
        aw0[c] = *(const float4*)(arow + c * 32);
        aw1[c] = *(const float4*)(arow + c * 32 + 4);
    }
    f32x4 acc[8];
#pragma unroll
    for (int j = 0; j < 8; ++j) acc[j] = (f32x4){0.f, 0.f, 0.f, 0.f};
    __syncthreads();   // single barrier of the kernel

#pragma unroll
    for (int c = 0; c < 4; ++c) {
        s8v ah, al;
        split8(aw0[c], aw1[c], ah, al);
#pragma unroll
        for (int j = 0; j < 8; ++j) {
            const s8v whf = *(const s8v*)&lh[((c * 8 + j) * 64 + lane) * 8];
            const s8v wlf = *(const s8v*)&ll[((c * 8 + j) * 64 + lane) * 8];
            acc[j] = __builtin_amdgcn_mfma_f32_16x16x32_bf16(ah, whf, acc[j], 0, 0, 0);
            acc[j] = __builtin_amdgcn_mfma_f32_16x16x32_bf16(ah, wlf, acc[j], 0, 0, 0);
            acc[j] = __builtin_amdgcn_mfma_f32_16x16x32_bf16(al, whf, acc[j], 0, 0, 0);
        }
    }

    // C/D layout: col = lane&15, row = quad*4 + reg
#pragma unroll
    for (int r = 0; r < 4; ++r) {
        const int gr = m0 + quad * 4 + r;
        if (gr >= M) continue;
#pragma unroll
        for (int j = 0; j < 8; ++j) {
            const int col = j * 16 + l16;
            const float v = acc[j][r];
            if (Cf) Cf[(long)gr * HBLK + col] = v;
            if (Ch16) Ch16[(long)gr * HBLK + col] = (_Float16)v;
        }
    }

    // fused attention-score epilogue (y==1 only)
    if (av) {
        float av0[8], av1[8];
#pragma unroll
        for (int j = 0; j < 8; ++j) {
            av0[j] = av[j * 16 + l16];
            av1[j] = av[128 + j * 16 + l16];
        }
#pragma unroll
        for (int r = 0; r < 4; ++r) {
            float ssp = 0.f, sdp = 0.f;
#pragma unroll
            for (int j = 0; j < 8; ++j) {
                const float v = acc[j][r];
                ssp += v * av0[j];
                sdp += v * av1[j];
            }
#pragma unroll
            for (int off = 1; off < 16; off <<= 1) {
                ssp += __shfl_xor(ssp, off);
                sdp += __shfl_xor(sdp, off);
            }
            const int gr = m0 + quad * 4 + r;
            if (l16 == 0 && gr < M) {
                sOut[gr] = ssp;
                dOut[gr] = sdp;
            }
        }
    }
}

// ---------------- output projection via MFMA: out[M x OUTD] = A @ Wout^T + b ----------------
__global__ __launch_bounds__(256) void gemm_out(
    const float* __restrict__ A,
    const short* __restrict__ Wh, const short* __restrict__ Wl,
    const float* __restrict__ bias, float* __restrict__ out,
    int M, int OUTD)
{
    __shared__ short lh[4096], ll[4096];
    const int tid = threadIdx.x;
    {
        const int4* gh = (const int4*)Wh;
        const int4* gl = (const int4*)Wl;
        int4* bh = (int4*)lh;
        int4* bl = (int4*)ll;
        bh[tid * 2] = gh[tid * 2];
        bh[tid * 2 + 1] = gh[tid * 2 + 1];
        bl[tid * 2] = gl[tid * 2];
        bl[tid * 2 + 1] = gl[tid * 2 + 1];
    }
    const int wv = tid >> 6;
    const int lane = tid & 63;
    const int l16 = lane & 15;
    const int quad = lane >> 4;
    const int m0 = blockIdx.x * 64 + wv * 16;
    int ra = m0 + l16;
    if (ra >= M) ra = M - 1;
    const float* arow = A + (long)ra * HBLK + quad * 8;

    f32x4 acc[2];
    acc[0] = (f32x4){0.f, 0.f, 0.f, 0.f};
    acc[1] = (f32x4){0.f, 0.f, 0.f, 0.f};
    __syncthreads();

#pragma unroll
    for (int c = 0; c < 4; ++c) {
        const float4 a0 = *(const float4*)(arow + c * 32);
        const float4 a1 = *(const float4*)(arow + c * 32 + 4);
        s8v ah, al;
        split8(a0, a1, ah, al);
#pragma unroll
        for (int j = 0; j < 2; ++j) {
            const s8v whf = *(const s8v*)&lh[((c * 2 + j) * 64 + lane) * 8];
            const s8v wlf = *(const s8v*)&ll[((c * 2 + j) * 64 + lane) * 8];
            acc[j] = __builtin_amdgcn_mfma_f32_16x16x32_bf16(ah, whf, acc[j], 0, 0, 0);
            acc[j] = __builtin_amdgcn_mfma_f32_16x16x32_bf16(ah, wlf, acc[j], 0, 0, 0);
            acc[j] = __builtin_amdgcn_mfma_f32_16x16x32_bf16(al, whf, acc[j], 0, 0, 0);
        }
    }

#pragma unroll
    for (int r = 0; r < 4; ++r) {
        const int gr = m0 + quad * 4 + r;
        if (gr >= M) continue;
#pragma unroll
        for (int j = 0; j < 2; ++j) {
            const int col = j * 16 + l16;
            if (col < OUTD)
                out[(long)gr * OUTD + col] = acc[j][r] + bias[col];
        }
    }
}

// ---------------- fused softmax + weighted gather; one wave per node ----------------
__global__ void gat_gather(const float* __restrict__ h_in, const float* __restrict__ hs,
                           const _Float16* __restrict__ zh,
                           const float* __restrict__ s_src, const float* __restrict__ s_dst,
                           const int* __restrict__ offs, const int* __restrict__ srcs,
                           float* __restrict__ h_out, int N) {
    const int wave = threadIdx.x >> 6;
    const int lane = threadIdx.x & 63;
    const int n = blockIdx.x * 4 + wave;
    if (n >= N) return;
    const int g = lane >> 4, l = lane & 15;
    const int beg = offs[n], end = offs[n + 1];

    float acc[8] = {};
    if (end > beg) {
        const float sd = s_dst[n];
        // pass 1: online softmax stats
        float m = -INFINITY, s = 0.f;
        for (int i = beg + lane; i < end; i += 64) {
            float e = sd + s_src[srcs[i]];
            e = e > 0.f ? e : 0.01f * e;
            float nm = fmaxf(m, e);
            s = s * __expf(m - nm) + __expf(e - nm);
            m = nm;
        }
#pragma unroll
        for (int off = 32; off > 0; off >>= 1) {
            float m2 = __shfl_down(m, off);
            float s2 = __shfl_down(s, off);
            if (m2 > m) {
                float t = m; m = m2; m2 = t;
                float ts = s; s = s2; s2 = ts;
            }
            s = (m == -INFINITY) ? 0.f : s + s2 * __expf(m2 - m);
        }
        m = __shfl(m, 0);
        s = __shfl(s, 0);
        const float inv = 1.f / fmaxf(s, 1e-16f);

        // pass 2: weighted gather, weight recomputed per edge
        int i = beg + g;
        for (; i + 4 < end; i += 8) {
            const int s0 = srcs[i];
            const int s1 = srcs[i + 4];
            float e0 = sd + s_src[s0];
            float e1 = sd + s_src[s1];
            e0 = e0 > 0.f ? e0 : 0.01f * e0;
            e1 = e1 > 0.f ? e1 : 0.01f * e1;
            const float w0 = __expf(e0 - m) * inv;
            const float w1 = __expf(e1 - m) * inv;
            const h8f z0 = *(const h8f*)(zh + (long)s0 * HBLK + 8 * l);
            const h8f z1 = *(const h8f*)(zh + (long)s1 * HBLK + 8 * l);
#pragma unroll
            for (int e = 0; e < 8; ++e)
                acc[e] += w0 * (float)z0[e] + w1 * (float)z1[e];
        }
        if (i < end) {
            const int s0 = srcs[i];
            float e0 = sd + s_src[s0];
            e0 = e0 > 0.f ? e0 : 0.01f * e0;
            const float w0 = __expf(e0 - m) * inv;
            const h8f z0 = *(const h8f*)(zh + (long)s0 * HBLK + 8 * l);
#pragma unroll
            for (int e = 0; e < 8; ++e)
                acc[e] += w0 * (float)z0[e];
        }
#pragma unroll
        for (int e = 0; e < 8; ++e) {
            acc[e] += __shfl_down(acc[e], 32);
            acc[e] += __shfl_down(acc[e], 16);
        }
    }

    if (g == 0) {
        const long base = (long)n * HBLK + 8 * l;
        const float4 hi0 = *(const float4*)(h_in + base);
        const float4 hi1 = *(const float4*)(h_in + base + 4);
        float o[8];
        if (end > beg) {
            const float4 hv0 = *(const float4*)(hs + base);
            const float4 hv1 = *(const float4*)(hs + base + 4);
            const float* hip = (const float*)&hi0;
            const float* hvp = (const float*)&hv0;
#pragma unroll
            for (int e = 0; e < 4; ++e) o[e] = hip[e] + hvp[e] + acc[e];
            const float* hip1 = (const float*)&hi1;
            const float* hvp1 = (const float*)&hv1;
#pragma unroll
            for (int e = 0; e < 4; ++e) o[4 + e] = hip1[e] + hvp1[e] + acc[4 + e];
        } else {  // DGL leaves h at h_in; residual doubles it
            const float* hip = (const float*)&hi0;
            const float* hip1 = (const float*)&hi1;
#pragma unroll
            for (int e = 0; e < 4; ++e) o[e] = 2.f * hip[e];
#pragma unroll
            for (int e = 0; e < 4; ++e) o[4 + e] = 2.f * hip1[e];
        }
        *(float4*)(h_out + base) = *(float4*)&o[0];
        *(float4*)(h_out + base + 4) = *(float4*)&o[4];
    }
}

extern "C" void kernel_launch(void* const* d_in, const int* in_sizes, int n_in,
                              void* d_out, int out_size, void* d_ws, size_t ws_size,
                              hipStream_t stream) {
    const float* feats = (const float*)d_in[0];
    const float* maps  = (const float*)d_in[2];
    const int* src = (const int*)d_in[4];
    const int* dst = (const int*)d_in[5];
    const float* W_eh  = (const float*)d_in[6];
    const float* b_eh  = (const float*)d_in[7];
    const float* W_cat = (const float*)d_in[10];
    const float* b_cat = (const float*)d_in[11];
    const float* Ws1 = (const float*)d_in[12];
    const float* Wf1 = (const float*)d_in[13];
    const float* a1  = (const float*)d_in[14];
    const float* Ws2 = (const float*)d_in[15];
    const float* Wf2 = (const float*)d_in[16];
    const float* a2  = (const float*)d_in[17];
    const float* W_out = (const float*)d_in[18];
    const float* b_out = (const float*)d_in[19];

    const int N = in_sizes[3];            // snorm_n is (N,1)
    const int E = in_sizes[4];
    const int IN_DIM = in_sizes[0] / N;   // 24
    const int MAPD = in_sizes[2] / N;     // 512
    const int OUTD = in_sizes[19];        // 24
    const int KCAT = MAPD + HBLK;         // 640 = W_cat leading dim
    const int KC = (MAPD + IN_DIM + 31) & ~31;  // 544: folded concat K, chunk-padded

    // ---- workspace layout ----
    char* p = (char*)d_ws;
    const size_t NH = (size_t)N * HBLK;
    float* hin  = (float*)p;  p += NH * 4;
    float* hs   = (float*)p;  p += NH * 4;
    float* hout = (float*)p;  p += NH * 4;
    _Float16* zh = (_Float16*)p; p += NH * 2;
    float* ssrc = (float*)p;  p += (size_t)N * 4;
    float* sdst = (float*)p;  p += (size_t)N * 4;
    int* counts = (int*)p;    p += (size_t)N * 4;
    int* cursor = (int*)p;    p += (size_t)N * 4;
    int* offs   = (int*)p;    p += (size_t)(N + 1) * 4;
    int* srcs   = (int*)p;    p += (size_t)E * 4;   // src payload, dst-sorted
    int* bsums  = (int*)p;    p += 256 * 4;
    float* Wcomb = (float*)p; p += (size_t)HBLK * IN_DIM * 4;
    float* bcomb = (float*)p; p += (size_t)HBLK * 4;
    p = (char*)(((uintptr_t)p + 15) & ~(uintptr_t)15);
    short* Wcat_h = (short*)p; p += (size_t)HBLK * KC * 2;
    short* Wcat_l = (short*)p; p += (size_t)HBLK * KC * 2;
    short* Wout_h = (short*)p; p += (size_t)32 * HBLK * 2;
    short* Wout_l = (short*)p; p += (size_t)32 * HBLK * 2;
    short* Wly_h = (short*)p;  p += (size_t)4 * HBLK * HBLK * 2;  // 4 matrices, 16384 shorts each
    short* Wly_l = (short*)p;  p += (size_t)4 * HBLK * HBLK * 2;

    // ---- CSR by dst (rebuilt every call; ws is poisoned between calls) ----
    const int nScanB = (N + 255) / 256;   // <= 256 for N <= 65536
    zero_counts<<<nScanB, 256, 0, stream>>>(counts, N);
    hist_k<<<(E + 255) / 256, 256, 0, stream>>>(dst, counts, E);
    scan1<<<nScanB, 256, 0, stream>>>(counts, offs, bsums, N);
    scan2<<<1, 256, 0, stream>>>(bsums, nScanB);
    scan3<<<nScanB, 256, 0, stream>>>(offs, cursor, bsums, N, E);
    fill_k<<<(E + 255) / 256, 256, 0, stream>>>(dst, src, cursor, srcs, E);

    // ---- weight fold + split+pack ----
    make_wcomb<<<(HBLK * IN_DIM + HBLK + 255) / 256, 256, 0, stream>>>(
        W_cat, KCAT, MAPD, W_eh, IN_DIM, b_eh, b_cat, Wcomb, bcomb);
    pack_wcat<<<(HBLK * KC + 255) / 256, 256, 0, stream>>>(
        W_cat, KCAT, MAPD, Wcomb, IN_DIM, Wcat_h, Wcat_l, KC);
    split_w_pack4<<<dim3(64, 4), 256, 0, stream>>>(Ws1, Wf1, Ws2, Wf2, Wly_h, Wly_l);
    split_w_pack<<<(32 * HBLK + 255) / 256, 256, 0, stream>>>(
        W_out, HBLK, HBLK, OUTD, Wout_h, Wout_l, 32, HBLK);

    const int gGrid = (N + 63) / 64;
    const int n4 = (N + 3) / 4;

    // ---- concat GEMM (front GEMM folded in): hin = relu(maps@Wc1^T + feats@Wcomb^T + bcomb)
    gemm_bigk<<<gGrid, 256, 0, stream>>>(
        maps, MAPD, MAPD, feats, IN_DIM, MAPD + IN_DIM, KC,
        Wcat_h, Wcat_l, bcomb, hin, N);

    // ---- GAT layer 1 ----
    gemm_smallk<<<dim3(gGrid, 2), 256, 0, stream>>>(
        hin, Wly_h, Wly_l, Wly_h + 16384, Wly_l + 16384,
        hs, zh, a1, ssrc, sdst, N);
    gat_gather<<<n4, 256, 0, stream>>>(hin, hs, zh, ssrc, sdst, offs, srcs, hout, N);

    // ---- GAT layer 2 ----
    gemm_smallk<<<dim3(gGrid, 2), 256, 0, stream>>>(
        hout, Wly_h + 32768, Wly_l + 32768, Wly_h + 49152, Wly_l + 49152,
        hs, zh, a2, ssrc, sdst, N);
    gat_gather<<<n4, 256, 0, stream>>>(hout, hs, zh, ssrc, sdst, offs, srcs, hin, N);

    // ---- output projection ----
    gemm_out<<<gGrid, 256, 0, stream>>>(hin, Wout_h, Wout_l, b_out, (float*)d_out, N, OUTD);
}

// Round 2
// 274.056 us; speedup vs baseline: 1.1954x; 1.1428x over previous
//
#include <hip/hip_runtime.h>

#define HBLK 128  // hidden width, fixed by problem
#define EPB 4096  // edges per binning block

typedef __attribute__((ext_vector_type(8))) short s8v;    // 8 bf16 in 4 VGPRs
typedef __attribute__((ext_vector_type(4))) float f32x4;  // MFMA accumulator
typedef __attribute__((ext_vector_type(8))) _Float16 h8f; // 8 fp16 = 16B

// split fp32 into bf16 hi + lo (truncation; residual <= 2^-16 |x|)
__device__ inline void split2(float x, short& h, short& l) {
    unsigned hb = __float_as_uint(x) & 0xFFFF0000u;
    float hf = __uint_as_float(hb);
    float lf = x - hf;
    h = (short)(hb >> 16);
    l = (short)(__float_as_uint(lf) >> 16);
}

__device__ inline void split8(const float4& a0, const float4& a1, s8v& ah, s8v& al) {
    float vv[8];
    *(float4*)&vv[0] = a0;
    *(float4*)&vv[4] = a1;
#pragma unroll
    for (int e = 0; e < 8; ++e) {
        short hh, ll;
        split2(vv[e], hh, ll);
        ah[e] = hh;
        al[e] = ll;
    }
}

// ================= CSR build: 2-level binning sort (no global atomics) =================
// bucket = dst >> 7 (128 nodes per bucket, <= 256 buckets for N <= 32768).
// pass 0: per-block LDS histogram over buckets -> histT[bucket*NB1 + block]
// scan  : exclusive scan of histT (256*NB1 entries) via 3-phase scan
// pass 1: re-read edges, LDS cursors -> (src,dst) into ebuf; per-(block,bucket)
//         writes are sequential streams (L2-local, one XCD) -> no line bouncing
// pass 2: one block per bucket: LDS counting sort over 128 node slots; writes
//         offs[] and srcs[]; scatter confined to the bucket's ~16KB window.

__global__ void bin_hist(const int* __restrict__ dst, int* __restrict__ histT,
                         int E, int NB1) {
    __shared__ int h[256];
    const int t = threadIdx.x, blk = blockIdx.x;
    h[t] = 0;
    __syncthreads();
    const int e0 = blk * EPB;
    const int e1 = min(E, e0 + EPB);
    for (int e = e0 + t; e < e1; e += 256)
        atomicAdd(&h[dst[e] >> 7], 1);
    __syncthreads();
    histT[t * NB1 + blk] = h[t];
}

// ---- parallel exclusive scan, 3 phases (n up to 256*256) ----
__global__ void scan1(const int* __restrict__ counts, int* __restrict__ offs,
                      int* __restrict__ bsums, int n) {
    __shared__ int lds[256];
    const int t = threadIdx.x;
    const int i = blockIdx.x * 256 + t;
    const int v = (i < n) ? counts[i] : 0;
    lds[t] = v;
    __syncthreads();
    for (int off = 1; off < 256; off <<= 1) {
        int add = (t >= off) ? lds[t - off] : 0;
        __syncthreads();
        lds[t] += add;
        __syncthreads();
    }
    if (i < n) offs[i] = lds[t] - v;          // exclusive within block
    if (t == 255) bsums[blockIdx.x] = lds[255];
}

__global__ void scan2(int* __restrict__ bsums, int nb) {
    __shared__ int lds[256];
    const int t = threadIdx.x;
    const int v = (t < nb) ? bsums[t] : 0;
    lds[t] = v;
    __syncthreads();
    for (int off = 1; off < 256; off <<= 1) {
        int add = (t >= off) ? lds[t - off] : 0;
        __syncthreads();
        lds[t] += add;
        __syncthreads();
    }
    if (t < nb) bsums[t] = lds[t] - v;        // exclusive block prefix
}

__global__ void scan3g(int* __restrict__ data, const int* __restrict__ bsums, int n) {
    const int i = blockIdx.x * 256 + threadIdx.x;
    if (i < n) data[i] += bsums[blockIdx.x];
}

__global__ void bin_scatter(const int* __restrict__ src, const int* __restrict__ dst,
                            const int* __restrict__ histT, int2* __restrict__ ebuf,
                            int E, int NB1) {
    __shared__ int cur[256];
    const int t = threadIdx.x, blk = blockIdx.x;
    cur[t] = histT[t * NB1 + blk];
    __syncthreads();
    const int e0 = blk * EPB;
    const int e1 = min(E, e0 + EPB);
    for (int e = e0 + t; e < e1; e += 256) {
        const int d = dst[e];
        const int p = atomicAdd(&cur[d >> 7], 1);
        ebuf[p] = make_int2(src[e], d);
    }
}

__global__ void bucket_sort(const int2* __restrict__ ebuf, const int* __restrict__ histT,
                            int* __restrict__ offs, int* __restrict__ srcs,
                            int N, int E, int NB1) {
    __shared__ int cnt[256];
    __shared__ int cur[256];
    const int t = threadIdx.x, b = blockIdx.x;
    const int ebase = histT[b * NB1];
    const int eend = (b + 1 < 256) ? histT[(b + 1) * NB1] : E;
    cnt[t] = 0;
    __syncthreads();
    for (int e = ebase + t; e < eend; e += 256)
        atomicAdd(&cnt[ebuf[e].y & 127], 1);
    __syncthreads();
    const int own = cnt[t];
    for (int off = 1; off < 256; off <<= 1) {
        int add = (t >= off) ? cnt[t - off] : 0;
        __syncthreads();
        cnt[t] += add;
        __syncthreads();
    }
    const int excl = cnt[t] - own;
    cur[t] = ebase + excl;
    const int node = (b << 7) + t;
    if (t < 128 && node < N) offs[node] = ebase + excl;
    if (b == 0 && t == 0) offs[N] = E;
    __syncthreads();
    for (int e = ebase + t; e < eend; e += 256) {
        const int2 ed = ebuf[e];
        const int p = atomicAdd(&cur[ed.y & 127], 1);
        srcs[p] = ed.x;
    }
}

// ---------------- algebraic fold: W_comb = W_cat[:,MAPD:] @ W_eh ----------------
// hin = relu([maps|feats@Weh^T+beh] @ Wcat^T + bcat)
//     = relu(maps @ Wc1^T + feats @ Wcomb^T + bcomb)
__global__ void make_wcomb(const float* __restrict__ Wcat, int ldw, int mapd,
                           const float* __restrict__ Weh, int indim,
                           const float* __restrict__ beh, const float* __restrict__ bcat,
                           float* __restrict__ Wcomb, float* __restrict__ bcomb) {
    const int i = blockIdx.x * 256 + threadIdx.x;
    const int total = HBLK * indim;
    if (i < total) {
        const int c = i / indim, k = i % indim;
        const float* wc = Wcat + (long)c * ldw + mapd;
        float s = 0.f;
        for (int j = 0; j < HBLK; ++j) s += wc[j] * Weh[j * indim + k];
        Wcomb[(long)c * indim + k] = s;
    } else if (i < total + HBLK) {
        const int c = i - total;
        const float* wc = Wcat + (long)c * ldw + mapd;
        float s = bcat[c];
        for (int j = 0; j < HBLK; ++j) s += wc[j] * beh[j];
        bcomb[c] = s;
    }
}

// ---------------- weight split + pack into MFMA-fragment order ----------------
// Chunk-major: off = ((chunk*(C/16) + j)*64 + quad*16 + l16)*8 + t
__global__ void split_w_pack(const float* __restrict__ W, int ldw, int kin, int cin,
                             short* __restrict__ dh, short* __restrict__ dl,
                             int C, int K) {
    long i = (long)blockIdx.x * 256 + threadIdx.x;
    if (i >= (long)C * K) return;
    int c = (int)(i / K), k = (int)(i % K);
    float x = (k < kin && c < cin) ? W[(long)c * ldw + k] : 0.f;
    short h, l;
    split2(x, h, l);
    int nj = C >> 4;
    int j = c >> 4, l16 = c & 15;
    int chunk = k >> 5, quad = (k >> 3) & 3, t = k & 7;
    long off = (((long)(chunk * nj + j) * 64) + quad * 16 + l16) * 8 + t;
    dh[off] = h;
    dl[off] = l;
}

// combined concat weight: k<mapd from Wcat, mapd<=k<mapd+indim from Wcomb, pad 0
__global__ void pack_wcat(const float* __restrict__ Wcat, int ldw, int mapd,
                          const float* __restrict__ Wcomb, int indim,
                          short* __restrict__ dh, short* __restrict__ dl, int K) {
    long i = (long)blockIdx.x * 256 + threadIdx.x;
    if (i >= (long)HBLK * K) return;
    int c = (int)(i / K), k = (int)(i % K);
    float x = 0.f;
    if (k < mapd) x = Wcat[(long)c * ldw + k];
    else if (k < mapd + indim) x = Wcomb[(long)c * indim + (k - mapd)];
    short h, l;
    split2(x, h, l);
    int j = c >> 4, l16 = c & 15;
    int chunk = k >> 5, quad = (k >> 3) & 3, t = k & 7;
    long off = (((long)(chunk * 8 + j) * 64) + quad * 16 + l16) * 8 + t;
    dh[off] = h;
    dl[off] = l;
}

// all four 128x128 layer weights in one launch; matrix m at offset m*16384 shorts
__global__ void split_w_pack4(const float* __restrict__ W0, const float* __restrict__ W1,
                              const float* __restrict__ W2, const float* __restrict__ W3,
                              short* __restrict__ dh, short* __restrict__ dl) {
    const float* Ws[4] = {W0, W1, W2, W3};
    const int m = blockIdx.y;
    long i = (long)blockIdx.x * 256 + threadIdx.x;   // < 16384
    int c = (int)(i >> 7), k = (int)(i & 127);
    float x = Ws[m][c * HBLK + k];
    short h, l;
    split2(x, h, l);
    int j = c >> 4, l16 = c & 15;
    int chunk = k >> 5, quad = (k >> 3) & 3, t = k & 7;
    long off = (long)m * 16384 + (((long)(chunk * 8 + j) * 64) + quad * 16 + l16) * 8 + t;
    dh[off] = h;
    dl[off] = l;
}

// ---------------- big-K split-fp32 MFMA GEMM (concat): dual-A, LDS double-buffer ----------------
// Barrier is raw s_barrier + lgkmcnt(0) only: the private A-register prefetch
// (2 chunks deep) stays in flight across the barrier instead of being drained
// by __syncthreads' vmcnt(0). Always applies bias + relu.
__global__ __launch_bounds__(256, 2) void gemm_bigk(
    const float* __restrict__ A1, int lda1, int K1,
    const float* __restrict__ A2, int lda2, int Kin,
    int K,
    const short* __restrict__ Wh, const short* __restrict__ Wl,
    const float* __restrict__ bias,
    float* __restrict__ Cf, int M)
{
    __shared__ short lds_h[2][4096];   // 8 KB per buffer (one 32-k chunk, hi)
    __shared__ short lds_l[2][4096];
    const int tid = threadIdx.x;
    const int wv = tid >> 6;
    const int lane = tid & 63;
    const int l16 = lane & 15;
    const int quad = lane >> 4;
    const int m0 = blockIdx.x * 64 + wv * 16;
    int ra = m0 + l16;
    if (ra >= M) ra = M - 1;
    const long r1 = (long)ra * lda1;
    const long r2 = (long)ra * lda2;
    const int NC = K >> 5;

    f32x4 acc[8];
#pragma unroll
    for (int j = 0; j < 8; ++j) acc[j] = (f32x4){0.f, 0.f, 0.f, 0.f};

#define LOAD_A(d0, d1, kb)                                      \
    {                                                           \
        const int col0 = (kb) + quad * 8;                       \
        if (col0 < K1) {                                        \
            const float* ap = A1 + r1 + col0;                   \
            d0 = *(const float4*)ap;                            \
            d1 = *(const float4*)(ap + 4);                      \
        } else if (col0 < Kin) {                                \
            const float* ap = A2 + r2 + (col0 - K1);            \
            d0 = *(const float4*)ap;                            \
            d1 = *(const float4*)(ap + 4);                      \
        } else {                                                \
            d0 = make_float4(0.f, 0.f, 0.f, 0.f);               \
            d1 = make_float4(0.f, 0.f, 0.f, 0.f);               \
        }                                                       \
    }
#define LOAD_W(c)                                               \
    {                                                           \
        const int4* gh = (const int4*)(Wh + (long)(c) * 4096);  \
        const int4* gl = (const int4*)(Wl + (long)(c) * 4096);  \
        wh0 = gh[tid * 2]; wh1 = gh[tid * 2 + 1];               \
        wl0 = gl[tid * 2]; wl1 = gl[tid * 2 + 1];               \
    }
#define WRITE_W(b)                                              \
    {                                                           \
        int4* bh = (int4*)lds_h[b];                             \
        int4* bl = (int4*)lds_l[b];                             \
        bh[tid * 2] = wh0; bh[tid * 2 + 1] = wh1;               \
        bl[tid * 2] = wl0; bl[tid * 2 + 1] = wl1;               \
    }

    int4 wh0, wh1, wl0, wl1;
    LOAD_W(0)
    WRITE_W(0)
    LOAD_W(1)                               // chunk 1 held in regs until next stage point
    float4 a0c, a1c, a0n, a1n;
    float4 a0p = make_float4(0.f, 0.f, 0.f, 0.f);
    float4 a1p = make_float4(0.f, 0.f, 0.f, 0.f);
    LOAD_A(a0c, a1c, 0)
    LOAD_A(a0n, a1n, 32)
    asm volatile("s_waitcnt lgkmcnt(0)" ::: "memory");
    __builtin_amdgcn_s_barrier();
    asm volatile("" ::: "memory");

    for (int c = 0; c < NC; ++c) {
        const int nb = c & 1;
        // issue A prefetch for chunk c+2 (stays outstanding across the barrier)
        if (c + 2 < NC) {
            LOAD_A(a0p, a1p, (c + 2) * 32)
        }
        // compute chunk c from LDS buffer nb
        s8v ah, al;
        split8(a0c, a1c, ah, al);
#pragma unroll
        for (int j = 0; j < 8; ++j) {
            const s8v whf = *(const s8v*)&lds_h[nb][(j * 64 + lane) * 8];
            const s8v wlf = *(const s8v*)&lds_l[nb][(j * 64 + lane) * 8];
            acc[j] = __builtin_amdgcn_mfma_f32_16x16x32_bf16(ah, whf, acc[j], 0, 0, 0);
            acc[j] = __builtin_amdgcn_mfma_f32_16x16x32_bf16(ah, wlf, acc[j], 0, 0, 0);
            acc[j] = __builtin_amdgcn_mfma_f32_16x16x32_bf16(al, whf, acc[j], 0, 0, 0);
        }
        if (c + 1 < NC) {
            WRITE_W(nb ^ 1)                 // stage chunk c+1 (regs); waits only W loads
            if (c + 2 < NC) LOAD_W(c + 2)   // prefetch chunk c+2 into regs
            asm volatile("s_waitcnt lgkmcnt(0)" ::: "memory");
            __builtin_amdgcn_s_barrier();
            asm volatile("" ::: "memory");
        }
        a0c = a0n; a1c = a1n; a0n = a0p; a1n = a1p;
    }
#undef LOAD_A
#undef LOAD_W
#undef WRITE_W

    // C/D layout: col = lane&15, row = quad*4 + reg  (verified m89/m91)
#pragma unroll
    for (int r = 0; r < 4; ++r) {
        const int gr = m0 + quad * 4 + r;
        if (gr >= M) continue;
#pragma unroll
        for (int j = 0; j < 8; ++j) {
            const int col = j * 16 + l16;
            float v = acc[j][r] + bias[col];
            Cf[(long)gr * HBLK + col] = fmaxf(v, 0.f);
        }
    }
}

// ---------------- small-K (=128) dual GEMM: whole W staged once, zero loop barriers ----------------
// y==0: C1f = A @ W1^T (f32).  y==1: Czh = fp16(A @ W2^T) plus fused attention-score
// epilogue s_src/s_dst from avec.  64 KB LDS -> 2 blocks/CU.
__global__ __launch_bounds__(256, 2) void gemm_smallk(
    const float* __restrict__ A,
    const short* __restrict__ W1h, const short* __restrict__ W1l,
    const short* __restrict__ W2h, const short* __restrict__ W2l,
    float* __restrict__ C1f, _Float16* __restrict__ Czh,
    const float* __restrict__ avec,
    float* __restrict__ sOut, float* __restrict__ dOut, int M)
{
    __shared__ short lh[16384];   // 32 KB: full 128x128 hi
    __shared__ short ll[16384];   // 32 KB: full 128x128 lo
    const short* __restrict__ Wh = blockIdx.y ? W2h : W1h;
    const short* __restrict__ Wl = blockIdx.y ? W2l : W1l;
    float* __restrict__ Cf = blockIdx.y ? nullptr : C1f;
    _Float16* __restrict__ Ch16 = blockIdx.y ? Czh : nullptr;
    const float* __restrict__ av = blockIdx.y ? avec : nullptr;
    const int tid = threadIdx.x;
    const int wv = tid >> 6;
    const int lane = tid & 63;
    const int l16 = lane & 15;
    const int quad = lane >> 4;
    const int m0 = blockIdx.x * 64 + wv * 16;
    int ra = m0 + l16;
    if (ra >= M) ra = M - 1;
    const float* arow = A + (long)ra * HBLK + quad * 8;

    {   // stage whole weight: 2048 int4 per half, 8 per thread
        const int4* gh = (const int4*)Wh;
        const int4* gl = (const int4*)Wl;
        int4* bh = (int4*)lh;
        int4* bl = (int4*)ll;
#pragma unroll
        for (int i = 0; i < 8; ++i) {
            bh[i * 256 + tid] = gh[i * 256 + tid];
            bl[i * 256 + tid] = gl[i * 256 + tid];
        }
    }
    // issue all A loads up front (8 outstanding vmem)
    float4 aw0[4], aw1[4];
#pragma unroll
    for (int c = 0; c < 4; ++c) {
        aw0[c] = *(const float4*)(arow + c * 32);
        aw1[c] = *(const float4*)(arow + c * 32 + 4);
    }
    f32x4 acc[8];
#pragma unroll
    for (int j = 0; j < 8; ++j) acc[j] = (f32x4){0.f, 0.f, 0.f, 0.f};
    __syncthreads();   // single barrier of the kernel

#pragma unroll
    for (int c = 0; c < 4; ++c) {
        s8v ah, al;
        split8(aw0[c], aw1[c], ah, al);
#pragma unroll
        for (int j = 0; j < 8; ++j) {
            const s8v whf = *(const s8v*)&lh[((c * 8 + j) * 64 + lane) * 8];
            const s8v wlf = *(const s8v*)&ll[((c * 8 + j) * 64 + lane) * 8];
            acc[j] = __builtin_amdgcn_mfma_f32_16x16x32_bf16(ah, whf, acc[j], 0, 0, 0);
            acc[j] = __builtin_amdgcn_mfma_f32_16x16x32_bf16(ah, wlf, acc[j], 0, 0, 0);
            acc[j] = __builtin_amdgcn_mfma_f32_16x16x32_bf16(al, whf, acc[j], 0, 0, 0);
        }
    }

    // C/D layout: col = lane&15, row = quad*4 + reg
#pragma unroll
    for (int r = 0; r < 4; ++r) {
        const int gr = m0 + quad * 4 + r;
        if (gr >= M) continue;
#pragma unroll
        for (int j = 0; j < 8; ++j) {
            const int col = j * 16 + l16;
            const float v = acc[j][r];
            if (Cf) Cf[(long)gr * HBLK + col] = v;
            if (Ch16) Ch16[(long)gr * HBLK + col] = (_Float16)v;
        }
    }

    // fused attention-score epilogue (y==1 only)
    if (av) {
        float av0[8], av1[8];
#pragma unroll
        for (int j = 0; j < 8; ++j) {
            av0[j] = av[j * 16 + l16];
            av1[j] = av[128 + j * 16 + l16];
        }
#pragma unroll
        for (int r = 0; r < 4; ++r) {
            float ssp = 0.f, sdp = 0.f;
#pragma unroll
            for (int j = 0; j < 8; ++j) {
                const float v = acc[j][r];
                ssp += v * av0[j];
                sdp += v * av1[j];
            }
#pragma unroll
            for (int off = 1; off < 16; off <<= 1) {
                ssp += __shfl_xor(ssp, off);
                sdp += __shfl_xor(sdp, off);
            }
            const int gr = m0 + quad * 4 + r;
            if (l16 == 0 && gr < M) {
                sOut[gr] = ssp;
                dOut[gr] = sdp;
            }
        }
    }
}

// ---------------- output projection via MFMA: out[M x OUTD] = A @ Wout^T + b ----------------
__global__ __launch_bounds__(256) void gemm_out(
    const float* __restrict__ A,
    const short* __restrict__ Wh, const short* __restrict__ Wl,
    const float* __restrict__ bias, float* __restrict__ out,
    int M, int OUTD)
{
    __shared__ short lh[4096], ll[4096];
    const int tid = threadIdx.x;
    {
        const int4* gh = (const int4*)Wh;
        const int4* gl = (const int4*)Wl;
        int4* bh = (int4*)lh;
        int4* bl = (int4*)ll;
        bh[tid * 2] = gh[tid * 2];
        bh[tid * 2 + 1] = gh[tid * 2 + 1];
        bl[tid * 2] = gl[tid * 2];
        bl[tid * 2 + 1] = gl[tid * 2 + 1];
    }
    const int wv = tid >> 6;
    const int lane = tid & 63;
    const int l16 = lane & 15;
    const int quad = lane >> 4;
    const int m0 = blockIdx.x * 64 + wv * 16;
    int ra = m0 + l16;
    if (ra >= M) ra = M - 1;
    const float* arow = A + (long)ra * HBLK + quad * 8;

    f32x4 acc[2];
    acc[0] = (f32x4){0.f, 0.f, 0.f, 0.f};
    acc[1] = (f32x4){0.f, 0.f, 0.f, 0.f};
    __syncthreads();

#pragma unroll
    for (int c = 0; c < 4; ++c) {
        const float4 a0 = *(const float4*)(arow + c * 32);
        const float4 a1 = *(const float4*)(arow + c * 32 + 4);
        s8v ah, al;
        split8(a0, a1, ah, al);
#pragma unroll
        for (int j = 0; j < 2; ++j) {
            const s8v whf = *(const s8v*)&lh[((c * 2 + j) * 64 + lane) * 8];
            const s8v wlf = *(const s8v*)&ll[((c * 2 + j) * 64 + lane) * 8];
            acc[j] = __builtin_amdgcn_mfma_f32_16x16x32_bf16(ah, whf, acc[j], 0, 0, 0);
            acc[j] = __builtin_amdgcn_mfma_f32_16x16x32_bf16(ah, wlf, acc[j], 0, 0, 0);
            acc[j] = __builtin_amdgcn_mfma_f32_16x16x32_bf16(al, whf, acc[j], 0, 0, 0);
        }
    }

#pragma unroll
    for (int r = 0; r < 4; ++r) {
        const int gr = m0 + quad * 4 + r;
        if (gr >= M) continue;
#pragma unroll
        for (int j = 0; j < 2; ++j) {
            const int col = j * 16 + l16;
            if (col < OUTD)
                out[(long)gr * OUTD + col] = acc[j][r] + bias[col];
        }
    }
}

// ---------------- fused softmax + weighted gather; one wave per node ----------------
__global__ void gat_gather(const float* __restrict__ h_in, const float* __restrict__ hs,
                           const _Float16* __restrict__ zh,
                           const float* __restrict__ s_src, const float* __restrict__ s_dst,
                           const int* __restrict__ offs, const int* __restrict__ srcs,
                           float* __restrict__ h_out, int N) {
    const int wave = threadIdx.x >> 6;
    const int lane = threadIdx.x & 63;
    const int n = blockIdx.x * 4 + wave;
    if (n >= N) return;
    const int g = lane >> 4, l = lane & 15;
    const int beg = offs[n], end = offs[n + 1];

    float acc[8] = {};
    if (end > beg) {
        const float sd = s_dst[n];
        // pass 1: online softmax stats
        float m = -INFINITY, s = 0.f;
        for (int i = beg + lane; i < end; i += 64) {
            float e = sd + s_src[srcs[i]];
            e = e > 0.f ? e : 0.01f * e;
            float nm = fmaxf(m, e);
            s = s * __expf(m - nm) + __expf(e - nm);
            m = nm;
        }
#pragma unroll
        for (int off = 32; off > 0; off >>= 1) {
            float m2 = __shfl_down(m, off);
            float s2 = __shfl_down(s, off);
            if (m2 > m) {
                float t = m; m = m2; m2 = t;
                float ts = s; s = s2; s2 = ts;
            }
            s = (m == -INFINITY) ? 0.f : s + s2 * __expf(m2 - m);
        }
        m = __shfl(m, 0);
        s = __shfl(s, 0);
        const float inv = 1.f / fmaxf(s, 1e-16f);

        // pass 2: weighted gather, weight recomputed per edge
        int i = beg + g;
        for (; i + 4 < end; i += 8) {
            const int s0 = srcs[i];
            const int s1 = srcs[i + 4];
            float e0 = sd + s_src[s0];
            float e1 = sd + s_src[s1];
            e0 = e0 > 0.f ? e0 : 0.01f * e0;
            e1 = e1 > 0.f ? e1 : 0.01f * e1;
            const float w0 = __expf(e0 - m) * inv;
            const float w1 = __expf(e1 - m) * inv;
            const h8f z0 = *(const h8f*)(zh + (long)s0 * HBLK + 8 * l);
            const h8f z1 = *(const h8f*)(zh + (long)s1 * HBLK + 8 * l);
#pragma unroll
            for (int e = 0; e < 8; ++e)
                acc[e] += w0 * (float)z0[e] + w1 * (float)z1[e];
        }
        if (i < end) {
            const int s0 = srcs[i];
            float e0 = sd + s_src[s0];
            e0 = e0 > 0.f ? e0 : 0.01f * e0;
            const float w0 = __expf(e0 - m) * inv;
            const h8f z0 = *(const h8f*)(zh + (long)s0 * HBLK + 8 * l);
#pragma unroll
            for (int e = 0; e < 8; ++e)
                acc[e] += w0 * (float)z0[e];
        }
#pragma unroll
        for (int e = 0; e < 8; ++e) {
            acc[e] += __shfl_down(acc[e], 32);
            acc[e] += __shfl_down(acc[e], 16);
        }
    }

    if (g == 0) {
        const long base = (long)n * HBLK + 8 * l;
        const float4 hi0 = *(const float4*)(h_in + base);
        const float4 hi1 = *(const float4*)(h_in + base + 4);
        float o[8];
        if (end > beg) {
            const float4 hv0 = *(const float4*)(hs + base);
            const float4 hv1 = *(const float4*)(hs + base + 4);
            const float* hip = (const float*)&hi0;
            const float* hvp = (const float*)&hv0;
#pragma unroll
            for (int e = 0; e < 4; ++e) o[e] = hip[e] + hvp[e] + acc[e];
            const float* hip1 = (const float*)&hi1;
            const float* hvp1 = (const float*)&hv1;
#pragma unroll
            for (int e = 0; e < 4; ++e) o[4 + e] = hip1[e] + hvp1[e] + acc[4 + e];
        } else {  // DGL leaves h at h_in; residual doubles it
            const float* hip = (const float*)&hi0;
            const float* hip1 = (const float*)&hi1;
#pragma unroll
            for (int e = 0; e < 4; ++e) o[e] = 2.f * hip[e];
#pragma unroll
            for (int e = 0; e < 4; ++e) o[4 + e] = 2.f * hip1[e];
        }
        *(float4*)(h_out + base) = *(float4*)&o[0];
        *(float4*)(h_out + base + 4) = *(float4*)&o[4];
    }
}

extern "C" void kernel_launch(void* const* d_in, const int* in_sizes, int n_in,
                              void* d_out, int out_size, void* d_ws, size_t ws_size,
                              hipStream_t stream) {
    const float* feats = (const float*)d_in[0];
    const float* maps  = (const float*)d_in[2];
    const int* src = (const int*)d_in[4];
    const int* dst = (const int*)d_in[5];
    const float* W_eh  = (const float*)d_in[6];
    const float* b_eh  = (const float*)d_in[7];
    const float* W_cat = (const float*)d_in[10];
    const float* b_cat = (const float*)d_in[11];
    const float* Ws1 = (const float*)d_in[12];
    const float* Wf1 = (const float*)d_in[13];
    const float* a1  = (const float*)d_in[14];
    const float* Ws2 = (const float*)d_in[15];
    const float* Wf2 = (const float*)d_in[16];
    const float* a2  = (const float*)d_in[17];
    const float* W_out = (const float*)d_in[18];
    const float* b_out = (const float*)d_in[19];

    const int N = in_sizes[3];            // snorm_n is (N,1)
    const int E = in_sizes[4];
    const int IN_DIM = in_sizes[0] / N;   // 24
    const int MAPD = in_sizes[2] / N;     // 512
    const int OUTD = in_sizes[19];        // 24
    const int KCAT = MAPD + HBLK;         // 640 = W_cat leading dim
    const int KC = (MAPD + IN_DIM + 31) & ~31;  // 544: folded concat K, chunk-padded

    // ---- workspace layout ----
    char* p = (char*)d_ws;
    const size_t NH = (size_t)N * HBLK;
    float* hin  = (float*)p;  p += NH * 4;
    float* hs   = (float*)p;  p += NH * 4;
    float* hout = (float*)p;  p += NH * 4;
    _Float16* zh = (_Float16*)p; p += NH * 2;
    float* ssrc = (float*)p;  p += (size_t)N * 4;
    float* sdst = (float*)p;  p += (size_t)N * 4;
    int* offs   = (int*)p;    p += (size_t)(N + 1) * 4;
    int* srcs   = (int*)p;    p += (size_t)E * 4;   // src payload, dst-sorted
    int* bsums  = (int*)p;    p += 256 * 4;
    int* histT  = (int*)p;    p += (size_t)256 * 256 * 4;  // [bucket][block] counts -> scanned bases
    float* Wcomb = (float*)p; p += (size_t)HBLK * IN_DIM * 4;
    float* bcomb = (float*)p; p += (size_t)HBLK * 4;
    p = (char*)(((uintptr_t)p + 15) & ~(uintptr_t)15);
    int2* ebuf = (int2*)p;    p += (size_t)E * 8;   // coarse-binned (src,dst)
    short* Wcat_h = (short*)p; p += (size_t)HBLK * KC * 2;
    short* Wcat_l = (short*)p; p += (size_t)HBLK * KC * 2;
    short* Wout_h = (short*)p; p += (size_t)32 * HBLK * 2;
    short* Wout_l = (short*)p; p += (size_t)32 * HBLK * 2;
    short* Wly_h = (short*)p;  p += (size_t)4 * HBLK * HBLK * 2;  // 4 matrices, 16384 shorts each
    short* Wly_l = (short*)p;  p += (size_t)4 * HBLK * HBLK * 2;

    // ---- CSR by dst: 2-level binning sort (no global atomics) ----
    const int NB1 = (E + EPB - 1) / EPB;       // binning blocks (<=256 for E<=1M)
    const int NBUCK = (N + 127) >> 7;          // 128-node buckets (<=256 for N<=32768)
    const int nHist = 256 * NB1;
    bin_hist<<<NB1, 256, 0, stream>>>(dst, histT, E, NB1);
    scan1<<<NB1, 256, 0, stream>>>(histT, histT, bsums, nHist);
    scan2<<<1, 256, 0, stream>>>(bsums, NB1);
    scan3g<<<NB1, 256, 0, stream>>>(histT, bsums, nHist);
    bin_scatter<<<NB1, 256, 0, stream>>>(src, dst, histT, ebuf, E, NB1);
    bucket_sort<<<NBUCK, 256, 0, stream>>>(ebuf, histT, offs, srcs, N, E, NB1);

    // ---- weight fold + split+pack ----
    make_wcomb<<<(HBLK * IN_DIM + HBLK + 255) / 256, 256, 0, stream>>>(
        W_cat, KCAT, MAPD, W_eh, IN_DIM, b_eh, b_cat, Wcomb, bcomb);
    pack_wcat<<<(HBLK * KC + 255) / 256, 256, 0, stream>>>(
        W_cat, KCAT, MAPD, Wcomb, IN_DIM, Wcat_h, Wcat_l, KC);
    split_w_pack4<<<dim3(64, 4), 256, 0, stream>>>(Ws1, Wf1, Ws2, Wf2, Wly_h, Wly_l);
    split_w_pack<<<(32 * HBLK + 255) / 256, 256, 0, stream>>>(
        W_out, HBLK, HBLK, OUTD, Wout_h, Wout_l, 32, HBLK);

    const int gGrid = (N + 63) / 64;
    const int n4 = (N + 3) / 4;

    // ---- concat GEMM (front GEMM folded in): hin = relu(maps@Wc1^T + feats@Wcomb^T + bcomb)
    gemm_bigk<<<gGrid, 256, 0, stream>>>(
        maps, MAPD, MAPD, feats, IN_DIM, MAPD + IN_DIM, KC,
        Wcat_h, Wcat_l, bcomb, hin, N);

    // ---- GAT layer 1 ----
    gemm_smallk<<<dim3(gGrid, 2), 256, 0, stream>>>(
        hin, Wly_h, Wly_l, Wly_h + 16384, Wly_l + 16384,
        hs, zh, a1, ssrc, sdst, N);
    gat_gather<<<n4, 256, 0, stream>>>(hin, hs, zh, ssrc, sdst, offs, srcs, hout, N);

    // ---- GAT layer 2 ----
    gemm_smallk<<<dim3(gGrid, 2), 256, 0, stream>>>(
        hout, Wly_h + 32768, Wly_l + 32768, Wly_h + 49152, Wly_l + 49152,
        hs, zh, a2, ssrc, sdst, N);
    gat_gather<<<n4, 256, 0, stream>>>(hout, hs, zh, ssrc, sdst, offs, srcs, hin, N);

    // ---- output projection ----
    gemm_out<<<gGrid, 256, 0, stream>>>(hin, Wout_h, Wout_l, b_out, (float*)d_out, N, OUTD);
}

// Round 3
// 270.310 us; speedup vs baseline: 1.2120x; 1.0139x over previous
//
#include <hip/hip_runtime.h>

#define HBLK 128  // hidden width, fixed by problem
#define EPB 4096  // edges per binning block

typedef __attribute__((ext_vector_type(8))) short s8v;    // 8 bf16 in 4 VGPRs
typedef __attribute__((ext_vector_type(4))) float f32x4;  // MFMA accumulator
typedef __attribute__((ext_vector_type(8))) _Float16 h8f; // 8 fp16 = 16B

// split fp32 into bf16 hi + lo (truncation; residual <= 2^-16 |x|)
__device__ inline void split2(float x, short& h, short& l) {
    unsigned hb = __float_as_uint(x) & 0xFFFF0000u;
    float hf = __uint_as_float(hb);
    float lf = x - hf;
    h = (short)(hb >> 16);
    l = (short)(__float_as_uint(lf) >> 16);
}

__device__ inline void split8(const float4& a0, const float4& a1, s8v& ah, s8v& al) {
    float vv[8];
    *(float4*)&vv[0] = a0;
    *(float4*)&vv[4] = a1;
#pragma unroll
    for (int e = 0; e < 8; ++e) {
        short hh, ll;
        split2(vv[e], hh, ll);
        ah[e] = hh;
        al[e] = ll;
    }
}

// ================= CSR build: 2-level binning sort (no global atomics) =================
// bucket = dst >> 7 (128 nodes per bucket).  histT[bucket*NB1 + block] layout puts the
// (bucket, block) lex order contiguous for the 3-phase scan; the bsums block-prefix add
// is folded into the consumers (no scan3g pass).

__global__ void bin_hist(const int* __restrict__ dst, int* __restrict__ histT,
                         int E, int NB1) {
    __shared__ int h[256];
    const int t = threadIdx.x, blk = blockIdx.x;
    h[t] = 0;
    __syncthreads();
    const int e0 = blk * EPB;
    const int e1 = min(E, e0 + EPB);
    for (int e = e0 + t; e < e1; e += 256)
        atomicAdd(&h[dst[e] >> 7], 1);
    __syncthreads();
    histT[t * NB1 + blk] = h[t];
}

// ---- parallel exclusive scan, phases 1-2 (n up to 256*256) ----
__global__ void scan1(const int* __restrict__ counts, int* __restrict__ offs,
                      int* __restrict__ bsums, int n) {
    __shared__ int lds[256];
    const int t = threadIdx.x;
    const int i = blockIdx.x * 256 + t;
    const int v = (i < n) ? counts[i] : 0;
    lds[t] = v;
    __syncthreads();
    for (int off = 1; off < 256; off <<= 1) {
        int add = (t >= off) ? lds[t - off] : 0;
        __syncthreads();
        lds[t] += add;
        __syncthreads();
    }
    if (i < n) offs[i] = lds[t] - v;          // exclusive within block
    if (t == 255) bsums[blockIdx.x] = lds[255];
}

__global__ void scan2(int* __restrict__ bsums, int nb) {
    __shared__ int lds[256];
    const int t = threadIdx.x;
    const int v = (t < nb) ? bsums[t] : 0;
    lds[t] = v;
    __syncthreads();
    for (int off = 1; off < 256; off <<= 1) {
        int add = (t >= off) ? lds[t - off] : 0;
        __syncthreads();
        lds[t] += add;
        __syncthreads();
    }
    if (t < nb) bsums[t] = lds[t] - v;        // exclusive block prefix
}

__global__ void bin_scatter(const int* __restrict__ src, const int* __restrict__ dst,
                            const int* __restrict__ histT, const int* __restrict__ bsums,
                            int2* __restrict__ ebuf, int E, int NB1) {
    __shared__ int cur[256];
    const int t = threadIdx.x, blk = blockIdx.x;
    const int li = t * NB1 + blk;
    cur[t] = histT[li] + bsums[li >> 8];      // folded scan3
    __syncthreads();
    const int e0 = blk * EPB;
    const int e1 = min(E, e0 + EPB);
    for (int e = e0 + t; e < e1; e += 256) {
        const int d = dst[e];
        const int p = atomicAdd(&cur[d >> 7], 1);
        ebuf[p] = make_int2(src[e], d);
    }
}

__global__ void bucket_sort(const int2* __restrict__ ebuf, const int* __restrict__ histT,
                            const int* __restrict__ bsums,
                            int* __restrict__ offs, int* __restrict__ srcs,
                            int N, int E, int NB1) {
    __shared__ int cnt[256];
    __shared__ int cur[256];
    const int t = threadIdx.x, b = blockIdx.x;
    const int li0 = b * NB1;
    const int ebase = histT[li0] + bsums[li0 >> 8];
    int eend = E;
    if (b + 1 < 256) {
        const int li1 = (b + 1) * NB1;
        eend = histT[li1] + bsums[li1 >> 8];
    }
    cnt[t] = 0;
    __syncthreads();
    for (int e = ebase + t; e < eend; e += 256)
        atomicAdd(&cnt[ebuf[e].y & 127], 1);
    __syncthreads();
    const int own = cnt[t];
    for (int off = 1; off < 256; off <<= 1) {
        int add = (t >= off) ? cnt[t - off] : 0;
        __syncthreads();
        cnt[t] += add;
        __syncthreads();
    }
    const int excl = cnt[t] - own;
    cur[t] = ebase + excl;
    const int node = (b << 7) + t;
    if (t < 128 && node < N) offs[node] = ebase + excl;
    if (b == 0 && t == 0) offs[N] = E;
    __syncthreads();
    for (int e = ebase + t; e < eend; e += 256) {
        const int2 ed = ebuf[e];
        const int p = atomicAdd(&cur[ed.y & 127], 1);
        srcs[p] = ed.x;
    }
}

// ---------------- combined concat-weight pack (W_eh fold computed inline) ----------------
// hin = relu([maps|feats@Weh^T+beh] @ Wcat^T + bcat)
//     = relu(maps @ Wc1^T + feats @ Wcomb^T + bcomb)
// k<mapd -> Wcat; mapd<=k<mapd+indim -> Wcomb[c][k-mapd] = dot(Wcat[c,mapd:], Weh[:,k-mapd]); pad 0.
// Tail threads (i >= HBLK*K) compute bcomb.
__global__ void pack_wcat(const float* __restrict__ Wcat, int ldw, int mapd,
                          const float* __restrict__ Weh, int indim,
                          const float* __restrict__ beh, const float* __restrict__ bcat,
                          short* __restrict__ dh, short* __restrict__ dl,
                          float* __restrict__ bcomb, int K) {
    const long i = (long)blockIdx.x * 256 + threadIdx.x;
    const long total = (long)HBLK * K;
    if (i < total) {
        const int c = (int)(i / K), k = (int)(i % K);
        float x = 0.f;
        if (k < mapd) {
            x = Wcat[(long)c * ldw + k];
        } else if (k < mapd + indim) {
            const float* wc = Wcat + (long)c * ldw + mapd;
            const int kk = k - mapd;
            float s = 0.f;
            for (int j = 0; j < HBLK; ++j) s += wc[j] * Weh[j * indim + kk];
            x = s;
        }
        short h, l;
        split2(x, h, l);
        const int j = c >> 4, l16 = c & 15;
        const int chunk = k >> 5, quad = (k >> 3) & 3, t = k & 7;
        const long off = (((long)(chunk * 8 + j) * 64) + quad * 16 + l16) * 8 + t;
        dh[off] = h;
        dl[off] = l;
    } else if (i < total + HBLK) {
        const int c = (int)(i - total);
        const float* wc = Wcat + (long)c * ldw + mapd;
        float s = bcat[c];
        for (int j = 0; j < HBLK; ++j) s += wc[j] * beh[j];
        bcomb[c] = s;
    }
}

// all four 128x128 layer weights + Wout in one launch
// y<4: layer matrix y at dh/dl + y*16384.  y==4: Wout (32x128 padded) into doh/dol.
__global__ void split_w_packA(const float* __restrict__ W0, const float* __restrict__ W1,
                              const float* __restrict__ W2, const float* __restrict__ W3,
                              const float* __restrict__ Wout, int outd,
                              short* __restrict__ dh, short* __restrict__ dl,
                              short* __restrict__ doh, short* __restrict__ dol) {
    const int m = blockIdx.y;
    const long i = (long)blockIdx.x * 256 + threadIdx.x;
    if (m < 4) {
        const float* Ws[4] = {W0, W1, W2, W3};
        const int c = (int)(i >> 7), k = (int)(i & 127);
        float x = Ws[m][c * HBLK + k];
        short h, l;
        split2(x, h, l);
        const int j = c >> 4, l16 = c & 15;
        const int chunk = k >> 5, quad = (k >> 3) & 3, t = k & 7;
        const long off = (long)m * 16384 + (((long)(chunk * 8 + j) * 64) + quad * 16 + l16) * 8 + t;
        dh[off] = h;
        dl[off] = l;
    } else {
        if (i >= 32 * HBLK) return;
        const int c = (int)(i >> 7), k = (int)(i & 127);
        float x = (c < outd) ? Wout[c * HBLK + k] : 0.f;
        short h, l;
        split2(x, h, l);
        const int j = c >> 4, l16 = c & 15;
        const int chunk = k >> 5, quad = (k >> 3) & 3, t = k & 7;
        const long off = (((long)(chunk * 2 + j) * 64) + quad * 16 + l16) * 8 + t;
        doh[off] = h;
        dol[off] = l;
    }
}

// ---------------- big-K split-fp32 MFMA GEMM (concat): deep-pipelined ----------------
// W prefetch 2 chunks deep (regs), A prefetch 3 chunks deep: every load has >=2 chunks
// (~800 cyc) of MFMA cover before its waitcnt.  Barrier is raw s_barrier + lgkmcnt(0)
// only -- outstanding global loads stay in flight across it.  Applies bias + relu.
__global__ __launch_bounds__(256, 2) void gemm_bigk(
    const float* __restrict__ A1, int lda1, int K1,
    const float* __restrict__ A2, int lda2, int Kin,
    int K,
    const short* __restrict__ Wh, const short* __restrict__ Wl,
    const float* __restrict__ bias,
    float* __restrict__ Cf, int M)
{
    __shared__ short lds_h[2][4096];   // 8 KB per buffer (one 32-k chunk, hi)
    __shared__ short lds_l[2][4096];
    const int tid = threadIdx.x;
    const int wv = tid >> 6;
    const int lane = tid & 63;
    const int l16 = lane & 15;
    const int quad = lane >> 4;
    const int m0 = blockIdx.x * 64 + wv * 16;
    int ra = m0 + l16;
    if (ra >= M) ra = M - 1;
    const long r1 = (long)ra * lda1;
    const long r2 = (long)ra * lda2;
    const int NC = K >> 5;

    f32x4 acc[8];
#pragma unroll
    for (int j = 0; j < 8; ++j) acc[j] = (f32x4){0.f, 0.f, 0.f, 0.f};

#define LOAD_A(d0, d1, kb)                                      \
    {                                                           \
        const int col0 = (kb) + quad * 8;                       \
        if (col0 < K1) {                                        \
            const float* ap = A1 + r1 + col0;                   \
            d0 = *(const float4*)ap;                            \
            d1 = *(const float4*)(ap + 4);                      \
        } else if (col0 < Kin) {                                \
            const float* ap = A2 + r2 + (col0 - K1);            \
            d0 = *(const float4*)ap;                            \
            d1 = *(const float4*)(ap + 4);                      \
        } else {                                                \
            d0 = make_float4(0.f, 0.f, 0.f, 0.f);               \
            d1 = make_float4(0.f, 0.f, 0.f, 0.f);               \
        }                                                       \
    }
#define LOAD_W(r0, r1w, r2w, r3, c)                             \
    {                                                           \
        const int4* gh = (const int4*)(Wh + (long)(c) * 4096);  \
        const int4* gl = (const int4*)(Wl + (long)(c) * 4096);  \
        r0 = gh[tid * 2]; r1w = gh[tid * 2 + 1];                \
        r2w = gl[tid * 2]; r3 = gl[tid * 2 + 1];                \
    }
#define WRITE_W(b, r0, r1w, r2w, r3)                            \
    {                                                           \
        int4* bh = (int4*)lds_h[b];                             \
        int4* bl = (int4*)lds_l[b];                             \
        bh[tid * 2] = r0; bh[tid * 2 + 1] = r1w;                \
        bl[tid * 2] = r2w; bl[tid * 2 + 1] = r3;                \
    }

    int4 wa0, wa1, wa2, wa3, wb0, wb1, wb2, wb3;
    LOAD_W(wa0, wa1, wa2, wa3, 0)
    WRITE_W(0, wa0, wa1, wa2, wa3)          // waits chunk-0 loads
    LOAD_W(wa0, wa1, wa2, wa3, 1)           // chunk 1 in regs (written at end of c=0)
    LOAD_W(wb0, wb1, wb2, wb3, 2)           // chunk 2 in regs (2-deep)
    float4 a0c, a1c, a0n, a1n, a0p, a1p;
    float4 a0q = make_float4(0.f, 0.f, 0.f, 0.f);
    float4 a1q = make_float4(0.f, 0.f, 0.f, 0.f);
    LOAD_A(a0c, a1c, 0)
    LOAD_A(a0n, a1n, 32)
    LOAD_A(a0p, a1p, 64)
    asm volatile("s_waitcnt lgkmcnt(0)" ::: "memory");
    __builtin_amdgcn_s_barrier();
    asm volatile("" ::: "memory");

    for (int c = 0; c < NC; ++c) {
        const int nb = c & 1;
        // A prefetch for chunk c+3 (stays outstanding across the barrier)
        if (c + 3 < NC) {
            LOAD_A(a0q, a1q, (c + 3) * 32)
        }
        // compute chunk c from LDS buffer nb
        s8v ah, al;
        split8(a0c, a1c, ah, al);
#pragma unroll
        for (int j = 0; j < 8; ++j) {
            const s8v whf = *(const s8v*)&lds_h[nb][(j * 64 + lane) * 8];
            const s8v wlf = *(const s8v*)&lds_l[nb][(j * 64 + lane) * 8];
            acc[j] = __builtin_amdgcn_mfma_f32_16x16x32_bf16(ah, whf, acc[j], 0, 0, 0);
            acc[j] = __builtin_amdgcn_mfma_f32_16x16x32_bf16(ah, wlf, acc[j], 0, 0, 0);
            acc[j] = __builtin_amdgcn_mfma_f32_16x16x32_bf16(al, whf, acc[j], 0, 0, 0);
        }
        if (c + 1 < NC) {
            WRITE_W(nb ^ 1, wa0, wa1, wa2, wa3)   // stage chunk c+1 (loaded 2 chunks ago)
            wa0 = wb0; wa1 = wb1; wa2 = wb2; wa3 = wb3;
            if (c + 3 < NC) LOAD_W(wb0, wb1, wb2, wb3, c + 3)
            asm volatile("s_waitcnt lgkmcnt(0)" ::: "memory");
            __builtin_amdgcn_s_barrier();
            asm volatile("" ::: "memory");
        }
        a0c = a0n; a1c = a1n;
        a0n = a0p; a1n = a1p;
        a0p = a0q; a1p = a1q;
    }
#undef LOAD_A
#undef LOAD_W
#undef WRITE_W

    // C/D layout: col = lane&15, row = quad*4 + reg  (verified m89/m91)
#pragma unroll
    for (int r = 0; r < 4; ++r) {
        const int gr = m0 + quad * 4 + r;
        if (gr >= M) continue;
#pragma unroll
        for (int j = 0; j < 8; ++j) {
            const int col = j * 16 + l16;
            float v = acc[j][r] + bias[col];
            Cf[(long)gr * HBLK + col] = fmaxf(v, 0.f);
        }
    }
}

// ---------------- small-K (=128) dual GEMM: whole W staged once, zero loop barriers ----------------
// y==0: C1f = A @ W1^T (f32).  y==1: Czh = fp16(A @ W2^T) plus fused attention-score
// epilogue s_src/s_dst from avec.  64 KB LDS -> 2 blocks/CU.
__global__ __launch_bounds__(256, 2) void gemm_smallk(
    const float* __restrict__ A,
    const short* __restrict__ W1h, const short* __restrict__ W1l,
    const short* __restrict__ W2h, const short* __restrict__ W2l,
    float* __restrict__ C1f, _Float16* __restrict__ Czh,
    const float* __restrict__ avec,
    float* __restrict__ sOut, float* __restrict__ dOut, int M)
{
    __shared__ short lh[16384];   // 32 KB: full 128x128 hi
    __shared__ short ll[16384];   // 32 KB: full 128x128 lo
    const short* __restrict__ Wh = blockIdx.y ? W2h : W1h;
    const short* __restrict__ Wl = blockIdx.y ? W2l : W1l;
    float* __restrict__ Cf = blockIdx.y ? nullptr : C1f;
    _Float16* __restrict__ Ch16 = blockIdx.y ? Czh : nullptr;
    const float* __restrict__ av = blockIdx.y ? avec : nullptr;
    const int tid = threadIdx.x;
    const int wv = tid >> 6;
    const int lane = tid & 63;
    const int l16 = lane & 15;
    const int quad = lane >> 4;
    const int m0 = blockIdx.x * 64 + wv * 16;
    int ra = m0 + l16;
    if (ra >= M) ra = M - 1;
    const float* arow = A + (long)ra * HBLK + quad * 8;

    {   // stage whole weight: 2048 int4 per half, 8 per thread
        const int4* gh = (const int4*)Wh;
        const int4* gl = (const int4*)Wl;
        int4* bh = (int4*)lh;
        int4* bl = (int4*)ll;
#pragma unroll
        for (int i = 0; i < 8; ++i) {
            bh[i * 256 + tid] = gh[i * 256 + tid];
            bl[i * 256 + tid] = gl[i * 256 + tid];
        }
    }
    // issue all A loads up front (8 outstanding vmem)
    float4 aw0[4], aw1[4];
#pragma unroll
    for (int c = 0; c < 4; ++c) {
        aw0[c] = *(const float4*)(arow + c * 32);
        aw1[c] = *(const float4*)(arow + c * 32 + 4);
    }
    f32x4 acc[8];
#pragma unroll
    for (int j = 0; j < 8; ++j) acc[j] = (f32x4){0.f, 0.f, 0.f, 0.f};
    __syncthreads();   // single barrier of the kernel

#pragma unroll
    for (int c = 0; c < 4; ++c) {
        s8v ah, al;
        split8(aw0[c], aw1[c], ah, al);
#pragma unroll
        for (int j = 0; j < 8; ++j) {
            const s8v whf = *(const s8v*)&lh[((c * 8 + j) * 64 + lane) * 8];
            const s8v wlf = *(const s8v*)&ll[((c * 8 + j) * 64 + lane) * 8];
            acc[j] = __builtin_amdgcn_mfma_f32_16x16x32_bf16(ah, whf, acc[j], 0, 0, 0);
            acc[j] = __builtin_amdgcn_mfma_f32_16x16x32_bf16(ah, wlf, acc[j], 0, 0, 0);
            acc[j] = __builtin_amdgcn_mfma_f32_16x16x32_bf16(al, whf, acc[j], 0, 0, 0);
        }
    }

    // C/D layout: col = lane&15, row = quad*4 + reg
#pragma unroll
    for (int r = 0; r < 4; ++r) {
        const int gr = m0 + quad * 4 + r;
        if (gr >= M) continue;
#pragma unroll
        for (int j = 0; j < 8; ++j) {
            const int col = j * 16 + l16;
            const float v = acc[j][r];
            if (Cf) Cf[(long)gr * HBLK + col] = v;
            if (Ch16) Ch16[(long)gr * HBLK + col] = (_Float16)v;
        }
    }

    // fused attention-score epilogue (y==1 only)
    if (av) {
        float av0[8], av1[8];
#pragma unroll
        for (int j = 0; j < 8; ++j) {
            av0[j] = av[j * 16 + l16];
            av1[j] = av[128 + j * 16 + l16];
        }
#pragma unroll
        for (int r = 0; r < 4; ++r) {
            float ssp = 0.f, sdp = 0.f;
#pragma unroll
            for (int j = 0; j < 8; ++j) {
                const float v = acc[j][r];
                ssp += v * av0[j];
                sdp += v * av1[j];
            }
#pragma unroll
            for (int off = 1; off < 16; off <<= 1) {
                ssp += __shfl_xor(ssp, off);
                sdp += __shfl_xor(sdp, off);
            }
            const int gr = m0 + quad * 4 + r;
            if (l16 == 0 && gr < M) {
                sOut[gr] = ssp;
                dOut[gr] = sdp;
            }
        }
    }
}

// ---------------- output projection via MFMA: out[M x OUTD] = A @ Wout^T + b ----------------
__global__ __launch_bounds__(256) void gemm_out(
    const float* __restrict__ A,
    const short* __restrict__ Wh, const short* __restrict__ Wl,
    const float* __restrict__ bias, float* __restrict__ out,
    int M, int OUTD)
{
    __shared__ short lh[4096], ll[4096];
    const int tid = threadIdx.x;
    {
        const int4* gh = (const int4*)Wh;
        const int4* gl = (const int4*)Wl;
        int4* bh = (int4*)lh;
        int4* bl = (int4*)ll;
        bh[tid * 2] = gh[tid * 2];
        bh[tid * 2 + 1] = gh[tid * 2 + 1];
        bl[tid * 2] = gl[tid * 2];
        bl[tid * 2 + 1] = gl[tid * 2 + 1];
    }
    const int wv = tid >> 6;
    const int lane = tid & 63;
    const int l16 = lane & 15;
    const int quad = lane >> 4;
    const int m0 = blockIdx.x * 64 + wv * 16;
    int ra = m0 + l16;
    if (ra >= M) ra = M - 1;
    const float* arow = A + (long)ra * HBLK + quad * 8;

    f32x4 acc[2];
    acc[0] = (f32x4){0.f, 0.f, 0.f, 0.f};
    acc[1] = (f32x4){0.f, 0.f, 0.f, 0.f};
    __syncthreads();

#pragma unroll
    for (int c = 0; c < 4; ++c) {
        const float4 a0 = *(const float4*)(arow + c * 32);
        const float4 a1 = *(const float4*)(arow + c * 32 + 4);
        s8v ah, al;
        split8(a0, a1, ah, al);
#pragma unroll
        for (int j = 0; j < 2; ++j) {
            const s8v whf = *(const s8v*)&lh[((c * 2 + j) * 64 + lane) * 8];
            const s8v wlf = *(const s8v*)&ll[((c * 2 + j) * 64 + lane) * 8];
            acc[j] = __builtin_amdgcn_mfma_f32_16x16x32_bf16(ah, whf, acc[j], 0, 0, 0);
            acc[j] = __builtin_amdgcn_mfma_f32_16x16x32_bf16(ah, wlf, acc[j], 0, 0, 0);
            acc[j] = __builtin_amdgcn_mfma_f32_16x16x32_bf16(al, whf, acc[j], 0, 0, 0);
        }
    }

#pragma unroll
    for (int r = 0; r < 4; ++r) {
        const int gr = m0 + quad * 4 + r;
        if (gr >= M) continue;
#pragma unroll
        for (int j = 0; j < 2; ++j) {
            const int col = j * 16 + l16;
            if (col < OUTD)
                out[(long)gr * OUTD + col] = acc[j][r] + bias[col];
        }
    }
}

// ---------------- fused softmax + weighted gather; one wave per node ----------------
// pass 2 is 4-way unrolled: 4 groups x 4 edges = 16 outstanding 16B gathers per wave.
__global__ void gat_gather(const float* __restrict__ h_in, const float* __restrict__ hs,
                           const _Float16* __restrict__ zh,
                           const float* __restrict__ s_src, const float* __restrict__ s_dst,
                           const int* __restrict__ offs, const int* __restrict__ srcs,
                           float* __restrict__ h_out, int N) {
    const int wave = threadIdx.x >> 6;
    const int lane = threadIdx.x & 63;
    const int n = blockIdx.x * 4 + wave;
    if (n >= N) return;
    const int g = lane >> 4, l = lane & 15;
    const int beg = offs[n], end = offs[n + 1];

    float acc[8] = {};
    if (end > beg) {
        const float sd = s_dst[n];
        // pass 1: online softmax stats
        float m = -INFINITY, s = 0.f;
        for (int i = beg + lane; i < end; i += 64) {
            float e = sd + s_src[srcs[i]];
            e = e > 0.f ? e : 0.01f * e;
            float nm = fmaxf(m, e);
            s = s * __expf(m - nm) + __expf(e - nm);
            m = nm;
        }
#pragma unroll
        for (int off = 32; off > 0; off >>= 1) {
            float m2 = __shfl_down(m, off);
            float s2 = __shfl_down(s, off);
            if (m2 > m) {
                float t = m; m = m2; m2 = t;
                float ts = s; s = s2; s2 = ts;
            }
            s = (m == -INFINITY) ? 0.f : s + s2 * __expf(m2 - m);
        }
        m = __shfl(m, 0);
        s = __shfl(s, 0);
        const float inv = 1.f / fmaxf(s, 1e-16f);

        // pass 2: weighted gather, weight recomputed per edge (4-way unroll)
        int i = beg + g;
        for (; i + 12 < end; i += 16) {
            const int s0 = srcs[i];
            const int s1 = srcs[i + 4];
            const int s2i = srcs[i + 8];
            const int s3 = srcs[i + 12];
            float e0 = sd + s_src[s0];
            float e1 = sd + s_src[s1];
            float e2 = sd + s_src[s2i];
            float e3 = sd + s_src[s3];
            e0 = e0 > 0.f ? e0 : 0.01f * e0;
            e1 = e1 > 0.f ? e1 : 0.01f * e1;
            e2 = e2 > 0.f ? e2 : 0.01f * e2;
            e3 = e3 > 0.f ? e3 : 0.01f * e3;
            const float w0 = __expf(e0 - m) * inv;
            const float w1 = __expf(e1 - m) * inv;
            const float w2 = __expf(e2 - m) * inv;
            const float w3 = __expf(e3 - m) * inv;
            const h8f z0 = *(const h8f*)(zh + (long)s0 * HBLK + 8 * l);
            const h8f z1 = *(const h8f*)(zh + (long)s1 * HBLK + 8 * l);
            const h8f z2 = *(const h8f*)(zh + (long)s2i * HBLK + 8 * l);
            const h8f z3 = *(const h8f*)(zh + (long)s3 * HBLK + 8 * l);
#pragma unroll
            for (int e = 0; e < 8; ++e)
                acc[e] += w0 * (float)z0[e] + w1 * (float)z1[e]
                        + w2 * (float)z2[e] + w3 * (float)z3[e];
        }
        for (; i < end; i += 4) {
            const int s0 = srcs[i];
            float e0 = sd + s_src[s0];
            e0 = e0 > 0.f ? e0 : 0.01f * e0;
            const float w0 = __expf(e0 - m) * inv;
            const h8f z0 = *(const h8f*)(zh + (long)s0 * HBLK + 8 * l);
#pragma unroll
            for (int e = 0; e < 8; ++e)
                acc[e] += w0 * (float)z0[e];
        }
        // combine the 4 groups (same col mapping)
#pragma unroll
        for (int e = 0; e < 8; ++e) {
            acc[e] += __shfl_down(acc[e], 32);
            acc[e] += __shfl_down(acc[e], 16);
        }
    }

    if (g == 0) {
        const long base = (long)n * HBLK + 8 * l;
        const float4 hi0 = *(const float4*)(h_in + base);
        const float4 hi1 = *(const float4*)(h_in + base + 4);
        float o[8];
        if (end > beg) {
            const float4 hv0 = *(const float4*)(hs + base);
            const float4 hv1 = *(const float4*)(hs + base + 4);
            const float* hip = (const float*)&hi0;
            const float* hvp = (const float*)&hv0;
#pragma unroll
            for (int e = 0; e < 4; ++e) o[e] = hip[e] + hvp[e] + acc[e];
            const float* hip1 = (const float*)&hi1;
            const float* hvp1 = (const float*)&hv1;
#pragma unroll
            for (int e = 0; e < 4; ++e) o[4 + e] = hip1[e] + hvp1[e] + acc[4 + e];
        } else {  // DGL leaves h at h_in; residual doubles it
            const float* hip = (const float*)&hi0;
            const float* hip1 = (const float*)&hi1;
#pragma unroll
            for (int e = 0; e < 4; ++e) o[e] = 2.f * hip[e];
#pragma unroll
            for (int e = 0; e < 4; ++e) o[4 + e] = 2.f * hip1[e];
        }
        *(float4*)(h_out + base) = *(float4*)&o[0];
        *(float4*)(h_out + base + 4) = *(float4*)&o[4];
    }
}

extern "C" void kernel_launch(void* const* d_in, const int* in_sizes, int n_in,
                              void* d_out, int out_size, void* d_ws, size_t ws_size,
                              hipStream_t stream) {
    const float* feats = (const float*)d_in[0];
    const float* maps  = (const float*)d_in[2];
    const int* src = (const int*)d_in[4];
    const int* dst = (const int*)d_in[5];
    const float* W_eh  = (const float*)d_in[6];
    const float* b_eh  = (const float*)d_in[7];
    const float* W_cat = (const float*)d_in[10];
    const float* b_cat = (const float*)d_in[11];
    const float* Ws1 = (const float*)d_in[12];
    const float* Wf1 = (const float*)d_in[13];
    const float* a1  = (const float*)d_in[14];
    const float* Ws2 = (const float*)d_in[15];
    const float* Wf2 = (const float*)d_in[16];
    const float* a2  = (const float*)d_in[17];
    const float* W_out = (const float*)d_in[18];
    const float* b_out = (const float*)d_in[19];

    const int N = in_sizes[3];            // snorm_n is (N,1)
    const int E = in_sizes[4];
    const int IN_DIM = in_sizes[0] / N;   // 24
    const int MAPD = in_sizes[2] / N;     // 512
    const int OUTD = in_sizes[19];        // 24
    const int KCAT = MAPD + HBLK;         // 640 = W_cat leading dim
    const int KC = (MAPD + IN_DIM + 31) & ~31;  // 544: folded concat K, chunk-padded

    // ---- workspace layout ----
    char* p = (char*)d_ws;
    const size_t NH = (size_t)N * HBLK;
    float* hin  = (float*)p;  p += NH * 4;
    float* hs   = (float*)p;  p += NH * 4;
    float* hout = (float*)p;  p += NH * 4;
    _Float16* zh = (_Float16*)p; p += NH * 2;
    float* ssrc = (float*)p;  p += (size_t)N * 4;
    float* sdst = (float*)p;  p += (size_t)N * 4;
    int* offs   = (int*)p;    p += (size_t)(N + 1) * 4;
    int* srcs   = (int*)p;    p += (size_t)E * 4;   // src payload, dst-sorted
    int* bsums  = (int*)p;    p += 256 * 4;
    int* histT  = (int*)p;    p += (size_t)256 * 256 * 4;  // [bucket][block] scanned counts
    float* bcomb = (float*)p; p += (size_t)HBLK * 4;
    p = (char*)(((uintptr_t)p + 15) & ~(uintptr_t)15);
    int2* ebuf = (int2*)p;    p += (size_t)E * 8;   // coarse-binned (src,dst)
    short* Wcat_h = (short*)p; p += (size_t)HBLK * KC * 2;
    short* Wcat_l = (short*)p; p += (size_t)HBLK * KC * 2;
    short* Wout_h = (short*)p; p += (size_t)32 * HBLK * 2;
    short* Wout_l = (short*)p; p += (size_t)32 * HBLK * 2;
    short* Wly_h = (short*)p;  p += (size_t)4 * HBLK * HBLK * 2;  // 4 matrices, 16384 shorts each
    short* Wly_l = (short*)p;  p += (size_t)4 * HBLK * HBLK * 2;

    // ---- CSR by dst: 2-level binning sort (no global atomics) ----
    const int NB1 = (E + EPB - 1) / EPB;       // binning blocks (<=256 for E<=1M)
    const int NBUCK = (N + 127) >> 7;          // 128-node buckets (<=256 for N<=32768)
    const int nHist = 256 * NB1;
    bin_hist<<<NB1, 256, 0, stream>>>(dst, histT, E, NB1);
    scan1<<<NB1, 256, 0, stream>>>(histT, histT, bsums, nHist);
    scan2<<<1, 256, 0, stream>>>(bsums, NB1);
    bin_scatter<<<NB1, 256, 0, stream>>>(src, dst, histT, bsums, ebuf, E, NB1);
    bucket_sort<<<NBUCK, 256, 0, stream>>>(ebuf, histT, bsums, offs, srcs, N, E, NB1);

    // ---- weight fold + split+pack (2 launches) ----
    pack_wcat<<<(HBLK * KC + HBLK + 255) / 256, 256, 0, stream>>>(
        W_cat, KCAT, MAPD, W_eh, IN_DIM, b_eh, b_cat, Wcat_h, Wcat_l, bcomb, KC);
    split_w_packA<<<dim3(64, 5), 256, 0, stream>>>(
        Ws1, Wf1, Ws2, Wf2, W_out, OUTD, Wly_h, Wly_l, Wout_h, Wout_l);

    const int gGrid = (N + 63) / 64;
    const int n4 = (N + 3) / 4;

    // ---- concat GEMM (front GEMM folded in): hin = relu(maps@Wc1^T + feats@Wcomb^T + bcomb)
    gemm_bigk<<<gGrid, 256, 0, stream>>>(
        maps, MAPD, MAPD, feats, IN_DIM, MAPD + IN_DIM, KC,
        Wcat_h, Wcat_l, bcomb, hin, N);

    // ---- GAT layer 1 ----
    gemm_smallk<<<dim3(gGrid, 2), 256, 0, stream>>>(
        hin, Wly_h, Wly_l, Wly_h + 16384, Wly_l + 16384,
        hs, zh, a1, ssrc, sdst, N);
    gat_gather<<<n4, 256, 0, stream>>>(hin, hs, zh, ssrc, sdst, offs, srcs, hout, N);

    // ---- GAT layer 2 ----
    gemm_smallk<<<dim3(gGrid, 2), 256, 0, stream>>>(
        hout, Wly_h + 32768, Wly_l + 32768, Wly_h + 49152, Wly_l + 49152,
        hs, zh, a2, ssrc, sdst, N);
    gat_gather<<<n4, 256, 0, stream>>>(hout, hs, zh, ssrc, sdst, offs, srcs, hin, N);

    // ---- output projection ----
    gemm_out<<<gGrid, 256, 0, stream>>>(hin, Wout_h, Wout_l, b_out, (float*)d_out, N, OUTD);
}

// Round 5
// 260.827 us; speedup vs baseline: 1.2561x; 1.0364x over previous
//
#include <hip/hip_runtime.h>

#define HBLK 128  // hidden width, fixed by problem
#define EPB 4096  // edges per binning block

typedef __attribute__((ext_vector_type(8))) short s8v;    // 8 bf16 in 4 VGPRs
typedef __attribute__((ext_vector_type(4))) float f32x4;  // MFMA accumulator
typedef __attribute__((ext_vector_type(8))) _Float16 h8f; // 8 fp16 = 16B

// split fp32 into bf16 hi + lo (truncation; residual <= 2^-16 |x|)
__device__ inline void split2(float x, short& h, short& l) {
    unsigned hb = __float_as_uint(x) & 0xFFFF0000u;
    float hf = __uint_as_float(hb);
    float lf = x - hf;
    h = (short)(hb >> 16);
    l = (short)(__float_as_uint(lf) >> 16);
}

__device__ inline void split8(const float4& a0, const float4& a1, s8v& ah, s8v& al) {
    float vv[8];
    *(float4*)&vv[0] = a0;
    *(float4*)&vv[4] = a1;
#pragma unroll
    for (int e = 0; e < 8; ++e) {
        short hh, ll;
        split2(vv[e], hh, ll);
        ah[e] = hh;
        al[e] = ll;
    }
}

// ================= CSR build: 2-level binning sort (no global atomics) =================
// bucket = dst >> 7 (128 nodes/bucket). ebuf entry packs (src<<7)|(dst&127) in one int.

__global__ void bin_hist(const int* __restrict__ dst, int* __restrict__ histT,
                         int E, int NB1) {
    __shared__ int h[256];
    const int t = threadIdx.x, blk = blockIdx.x;
    h[t] = 0;
    __syncthreads();
    const int e0 = blk * EPB;
    const int e1 = min(E, e0 + EPB);
    for (int e = e0 + t; e < e1; e += 256)
        atomicAdd(&h[dst[e] >> 7], 1);
    __syncthreads();
    histT[t * NB1 + blk] = h[t];
}

__global__ void scan1(const int* __restrict__ counts, int* __restrict__ offs,
                      int* __restrict__ bsums, int n) {
    __shared__ int lds[256];
    const int t = threadIdx.x;
    const int i = blockIdx.x * 256 + t;
    const int v = (i < n) ? counts[i] : 0;
    lds[t] = v;
    __syncthreads();
    for (int off = 1; off < 256; off <<= 1) {
        int add = (t >= off) ? lds[t - off] : 0;
        __syncthreads();
        lds[t] += add;
        __syncthreads();
    }
    if (i < n) offs[i] = lds[t] - v;          // exclusive within block
    if (t == 255) bsums[blockIdx.x] = lds[255];
}

__global__ void scan2(int* __restrict__ bsums, int nb) {
    __shared__ int lds[256];
    const int t = threadIdx.x;
    const int v = (t < nb) ? bsums[t] : 0;
    lds[t] = v;
    __syncthreads();
    for (int off = 1; off < 256; off <<= 1) {
        int add = (t >= off) ? lds[t - off] : 0;
        __syncthreads();
        lds[t] += add;
        __syncthreads();
    }
    if (t < nb) bsums[t] = lds[t] - v;        // exclusive block prefix
}

__global__ void bin_scatter(const int* __restrict__ src, const int* __restrict__ dst,
                            const int* __restrict__ histT, const int* __restrict__ bsums,
                            int* __restrict__ ebuf, int E, int NB1) {
    __shared__ int cur[256];
    const int t = threadIdx.x, blk = blockIdx.x;
    const int li = t * NB1 + blk;
    cur[t] = histT[li] + bsums[li >> 8];      // folded scan3
    __syncthreads();
    const int e0 = blk * EPB;
    const int e1 = min(E, e0 + EPB);
    for (int e = e0 + t; e < e1; e += 256) {
        const int d = dst[e];
        const int p = atomicAdd(&cur[d >> 7], 1);
        ebuf[p] = (src[e] << 7) | (d & 127);
    }
}

__global__ void bucket_sort(const int* __restrict__ ebuf, const int* __restrict__ histT,
                            const int* __restrict__ bsums,
                            int* __restrict__ offs, int* __restrict__ srcs,
                            int N, int E, int NB1) {
    __shared__ int cnt[256];
    __shared__ int cur[256];
    const int t = threadIdx.x, b = blockIdx.x;
    const int li0 = b * NB1;
    const int ebase = histT[li0] + bsums[li0 >> 8];
    int eend = E;
    if (b + 1 < 256) {
        const int li1 = (b + 1) * NB1;
        eend = histT[li1] + bsums[li1 >> 8];
    }
    cnt[t] = 0;
    __syncthreads();
    for (int e = ebase + t; e < eend; e += 256)
        atomicAdd(&cnt[ebuf[e] & 127], 1);
    __syncthreads();
    const int own = cnt[t];
    for (int off = 1; off < 256; off <<= 1) {
        int add = (t >= off) ? cnt[t - off] : 0;
        __syncthreads();
        cnt[t] += add;
        __syncthreads();
    }
    const int excl = cnt[t] - own;
    cur[t] = ebase + excl;
    const int node = (b << 7) + t;
    if (t < 128 && node < N) offs[node] = ebase + excl;
    if (b == 0 && t == 0) offs[N] = E;
    __syncthreads();
    for (int e = ebase + t; e < eend; e += 256) {
        const int ed = ebuf[e];
        const int p = atomicAdd(&cur[ed & 127], 1);
        srcs[p] = ed >> 7;
    }
}

// ---------------- combined concat-weight pack (W_eh fold computed inline) ----------------
__global__ void pack_wcat(const float* __restrict__ Wcat, int ldw, int mapd,
                          const float* __restrict__ Weh, int indim,
                          const float* __restrict__ beh, const float* __restrict__ bcat,
                          short* __restrict__ dh, short* __restrict__ dl,
                          float* __restrict__ bcomb, int K) {
    const long i = (long)blockIdx.x * 256 + threadIdx.x;
    const long total = (long)HBLK * K;
    if (i < total) {
        const int c = (int)(i / K), k = (int)(i % K);
        float x = 0.f;
        if (k < mapd) {
            x = Wcat[(long)c * ldw + k];
        } else if (k < mapd + indim) {
            const float* wc = Wcat + (long)c * ldw + mapd;
            const int kk = k - mapd;
            float s = 0.f;
            for (int j = 0; j < HBLK; ++j) s += wc[j] * Weh[j * indim + kk];
            x = s;
        }
        short h, l;
        split2(x, h, l);
        const int j = c >> 4, l16 = c & 15;
        const int chunk = k >> 5, quad = (k >> 3) & 3, t = k & 7;
        const long off = (((long)(chunk * 8 + j) * 64) + quad * 16 + l16) * 8 + t;
        dh[off] = h;
        dl[off] = l;
    } else if (i < total + HBLK) {
        const int c = (int)(i - total);
        const float* wc = Wcat + (long)c * ldw + mapd;
        float s = bcat[c];
        for (int j = 0; j < HBLK; ++j) s += wc[j] * beh[j];
        bcomb[c] = s;
    }
}

// all four 128x128 layer weights + Wout in one launch
// y<4: layer matrix y at dh/dl + y*16384.  y==4: Wout (32x128 padded) into doh/dol.
__global__ void split_w_packA(const float* __restrict__ W0, const float* __restrict__ W1,
                              const float* __restrict__ W2, const float* __restrict__ W3,
                              const float* __restrict__ Wout, int outd,
                              short* __restrict__ dh, short* __restrict__ dl,
                              short* __restrict__ doh, short* __restrict__ dol) {
    const int m = blockIdx.y;
    const long i = (long)blockIdx.x * 256 + threadIdx.x;
    if (m < 4) {
        const float* Ws[4] = {W0, W1, W2, W3};
        const int c = (int)(i >> 7), k = (int)(i & 127);
        float x = Ws[m][c * HBLK + k];
        short h, l;
        split2(x, h, l);
        const int j = c >> 4, l16 = c & 15;
        const int chunk = k >> 5, quad = (k >> 3) & 3, t = k & 7;
        const long off = (long)m * 16384 + (((long)(chunk * 8 + j) * 64) + quad * 16 + l16) * 8 + t;
        dh[off] = h;
        dl[off] = l;
    } else {
        if (i >= 32 * HBLK) return;
        const int c = (int)(i >> 7), k = (int)(i & 127);
        float x = (c < outd) ? Wout[c * HBLK + k] : 0.f;
        short h, l;
        split2(x, h, l);
        const int j = c >> 4, l16 = c & 15;
        const int chunk = k >> 5, quad = (k >> 3) & 3, t = k & 7;
        const long off = (((long)(chunk * 2 + j) * 64) + quad * 16 + l16) * 8 + t;
        doh[off] = h;
        dol[off] = l;
    }
}

// ---------------- big-K split-fp32 MFMA GEMM (concat): deep-pipelined ----------------
__global__ __launch_bounds__(256, 2) void gemm_bigk(
    const float* __restrict__ A1, int lda1, int K1,
    const float* __restrict__ A2, int lda2, int Kin,
    int K,
    const short* __restrict__ Wh, const short* __restrict__ Wl,
    const float* __restrict__ bias,
    float* __restrict__ Cf, int M)
{
    __shared__ short lds_h[2][4096];
    __shared__ short lds_l[2][4096];
    const int tid = threadIdx.x;
    const int wv = tid >> 6;
    const int lane = tid & 63;
    const int l16 = lane & 15;
    const int quad = lane >> 4;
    const int m0 = blockIdx.x * 64 + wv * 16;
    int ra = m0 + l16;
    if (ra >= M) ra = M - 1;
    const long r1 = (long)ra * lda1;
    const long r2 = (long)ra * lda2;
    const int NC = K >> 5;

    f32x4 acc[8];
#pragma unroll
    for (int j = 0; j < 8; ++j) acc[j] = (f32x4){0.f, 0.f, 0.f, 0.f};

#define LOAD_A(d0, d1, kb)                                      \
    {                                                           \
        const int col0 = (kb) + quad * 8;                       \
        if (col0 < K1) {                                        \
            const float* ap = A1 + r1 + col0;                   \
            d0 = *(const float4*)ap;                            \
            d1 = *(const float4*)(ap + 4);                      \
        } else if (col0 < Kin) {                                \
            const float* ap = A2 + r2 + (col0 - K1);            \
            d0 = *(const float4*)ap;                            \
            d1 = *(const float4*)(ap + 4);                      \
        } else {                                                \
            d0 = make_float4(0.f, 0.f, 0.f, 0.f);               \
            d1 = make_float4(0.f, 0.f, 0.f, 0.f);               \
        }                                                       \
    }
#define LOAD_W(r0, r1w, r2w, r3, c)                             \
    {                                                           \
        const int4* gh = (const int4*)(Wh + (long)(c) * 4096);  \
        const int4* gl = (const int4*)(Wl + (long)(c) * 4096);  \
        r0 = gh[tid * 2]; r1w = gh[tid * 2 + 1];                \
        r2w = gl[tid * 2]; r3 = gl[tid * 2 + 1];                \
    }
#define WRITE_W(b, r0, r1w, r2w, r3)                            \
    {                                                           \
        int4* bh = (int4*)lds_h[b];                             \
        int4* bl = (int4*)lds_l[b];                             \
        bh[tid * 2] = r0; bh[tid * 2 + 1] = r1w;                \
        bl[tid * 2] = r2w; bl[tid * 2 + 1] = r3;                \
    }

    int4 wa0, wa1, wa2, wa3, wb0, wb1, wb2, wb3;
    LOAD_W(wa0, wa1, wa2, wa3, 0)
    WRITE_W(0, wa0, wa1, wa2, wa3)
    LOAD_W(wa0, wa1, wa2, wa3, 1)
    LOAD_W(wb0, wb1, wb2, wb3, 2)
    float4 a0c, a1c, a0n, a1n, a0p, a1p;
    float4 a0q = make_float4(0.f, 0.f, 0.f, 0.f);
    float4 a1q = make_float4(0.f, 0.f, 0.f, 0.f);
    LOAD_A(a0c, a1c, 0)
    LOAD_A(a0n, a1n, 32)
    LOAD_A(a0p, a1p, 64)
    asm volatile("s_waitcnt lgkmcnt(0)" ::: "memory");
    __builtin_amdgcn_s_barrier();
    asm volatile("" ::: "memory");

    for (int c = 0; c < NC; ++c) {
        const int nb = c & 1;
        if (c + 3 < NC) {
            LOAD_A(a0q, a1q, (c + 3) * 32)
        }
        s8v ah, al;
        split8(a0c, a1c, ah, al);
#pragma unroll
        for (int j = 0; j < 8; ++j) {
            const s8v whf = *(const s8v*)&lds_h[nb][(j * 64 + lane) * 8];
            const s8v wlf = *(const s8v*)&lds_l[nb][(j * 64 + lane) * 8];
            acc[j] = __builtin_amdgcn_mfma_f32_16x16x32_bf16(ah, whf, acc[j], 0, 0, 0);
            acc[j] = __builtin_amdgcn_mfma_f32_16x16x32_bf16(ah, wlf, acc[j], 0, 0, 0);
            acc[j] = __builtin_amdgcn_mfma_f32_16x16x32_bf16(al, whf, acc[j], 0, 0, 0);
        }
        if (c + 1 < NC) {
            WRITE_W(nb ^ 1, wa0, wa1, wa2, wa3)
            wa0 = wb0; wa1 = wb1; wa2 = wb2; wa3 = wb3;
            if (c + 3 < NC) LOAD_W(wb0, wb1, wb2, wb3, c + 3)
            asm volatile("s_waitcnt lgkmcnt(0)" ::: "memory");
            __builtin_amdgcn_s_barrier();
            asm volatile("" ::: "memory");
        }
        a0c = a0n; a1c = a1n;
        a0n = a0p; a1n = a1p;
        a0p = a0q; a1p = a1q;
    }
#undef LOAD_A
#undef LOAD_W
#undef WRITE_W

#pragma unroll
    for (int r = 0; r < 4; ++r) {
        const int gr = m0 + quad * 4 + r;
        if (gr >= M) continue;
#pragma unroll
        for (int j = 0; j < 8; ++j) {
            const int col = j * 16 + l16;
            float v = acc[j][r] + bias[col];
            Cf[(long)gr * HBLK + col] = fmaxf(v, 0.f);
        }
    }
}

// ---------------- small-K (=128) dual GEMM: whole W staged once, zero loop barriers ----------------
// y==0: C1f = A @ W1^T (f32).  y==1: Czh = fp16(A @ W2^T) plus fused attention-score
// epilogue s_src/s_dst from avec.  64 KB LDS -> 2 blocks/CU.
__global__ __launch_bounds__(256, 2) void gemm_smallk(
    const float* __restrict__ A,
    const short* __restrict__ W1h, const short* __restrict__ W1l,
    const short* __restrict__ W2h, const short* __restrict__ W2l,
    float* __restrict__ C1f, _Float16* __restrict__ Czh,
    const float* __restrict__ avec,
    float* __restrict__ sOut, float* __restrict__ dOut, int M)
{
    __shared__ short lh[16384];   // 32 KB: full 128x128 hi
    __shared__ short ll[16384];   // 32 KB: full 128x128 lo
    const short* __restrict__ Wh = blockIdx.y ? W2h : W1h;
    const short* __restrict__ Wl = blockIdx.y ? W2l : W1l;
    float* __restrict__ Cf = blockIdx.y ? nullptr : C1f;
    _Float16* __restrict__ Ch16 = blockIdx.y ? Czh : nullptr;
    const float* __restrict__ av = blockIdx.y ? avec : nullptr;
    const int tid = threadIdx.x;
    const int wv = tid >> 6;
    const int lane = tid & 63;
    const int l16 = lane & 15;
    const int quad = lane >> 4;
    const int m0 = blockIdx.x * 64 + wv * 16;
    int ra = m0 + l16;
    if (ra >= M) ra = M - 1;
    const float* arow = A + (long)ra * HBLK + quad * 8;

    {   // stage whole weight: 2048 int4 per half, 8 per thread
        const int4* gh = (const int4*)Wh;
        const int4* gl = (const int4*)Wl;
        int4* bh = (int4*)lh;
        int4* bl = (int4*)ll;
#pragma unroll
        for (int i = 0; i < 8; ++i) {
            bh[i * 256 + tid] = gh[i * 256 + tid];
            bl[i * 256 + tid] = gl[i * 256 + tid];
        }
    }
    // issue all A loads up front (8 outstanding vmem)
    float4 aw0[4], aw1[4];
#pragma unroll
    for (int c = 0; c < 4; ++c) {
        aw0[c] = *(const float4*)(arow + c * 32);
        aw1[c] = *(const float4*)(arow + c * 32 + 4);
    }
    f32x4 acc[8];
#pragma unroll
    for (int j = 0; j < 8; ++j) acc[j] = (f32x4){0.f, 0.f, 0.f, 0.f};
    __syncthreads();   // single barrier of the kernel

#pragma unroll
    for (int c = 0; c < 4; ++c) {
        s8v ah, al;
        split8(aw0[c], aw1[c], ah, al);
#pragma unroll
        for (int j = 0; j < 8; ++j) {
            const s8v whf = *(const s8v*)&lh[((c * 8 + j) * 64 + lane) * 8];
            const s8v wlf = *(const s8v*)&ll[((c * 8 + j) * 64 + lane) * 8];
            acc[j] = __builtin_amdgcn_mfma_f32_16x16x32_bf16(ah, whf, acc[j], 0, 0, 0);
            acc[j] = __builtin_amdgcn_mfma_f32_16x16x32_bf16(ah, wlf, acc[j], 0, 0, 0);
            acc[j] = __builtin_amdgcn_mfma_f32_16x16x32_bf16(al, whf, acc[j], 0, 0, 0);
        }
    }

    // C/D layout: col = lane&15, row = quad*4 + reg
#pragma unroll
    for (int r = 0; r < 4; ++r) {
        const int gr = m0 + quad * 4 + r;
        if (gr >= M) continue;
#pragma unroll
        for (int j = 0; j < 8; ++j) {
            const int col = j * 16 + l16;
            const float v = acc[j][r];
            if (Cf) Cf[(long)gr * HBLK + col] = v;
            if (Ch16) Ch16[(long)gr * HBLK + col] = (_Float16)v;
        }
    }

    // fused attention-score epilogue (y==1 only)
    if (av) {
        float av0[8], av1[8];
#pragma unroll
        for (int j = 0; j < 8; ++j) {
            av0[j] = av[j * 16 + l16];
            av1[j] = av[128 + j * 16 + l16];
        }
#pragma unroll
        for (int r = 0; r < 4; ++r) {
            float ssp = 0.f, sdp = 0.f;
#pragma unroll
            for (int j = 0; j < 8; ++j) {
                const float v = acc[j][r];
                ssp += v * av0[j];
                sdp += v * av1[j];
            }
#pragma unroll
            for (int off = 1; off < 16; off <<= 1) {
                ssp += __shfl_xor(ssp, off);
                sdp += __shfl_xor(sdp, off);
            }
            const int gr = m0 + quad * 4 + r;
            if (l16 == 0 && gr < M) {
                sOut[gr] = ssp;
                dOut[gr] = sdp;
            }
        }
    }
}

// ---------------- output projection via MFMA: out[M x OUTD] = A @ Wout^T + b ----------------
__global__ __launch_bounds__(256) void gemm_out(
    const float* __restrict__ A,
    const short* __restrict__ Wh, const short* __restrict__ Wl,
    const float* __restrict__ bias, float* __restrict__ out,
    int M, int OUTD)
{
    __shared__ short lh[4096], ll[4096];
    const int tid = threadIdx.x;
    {
        const int4* gh = (const int4*)Wh;
        const int4* gl = (const int4*)Wl;
        int4* bh = (int4*)lh;
        int4* bl = (int4*)ll;
        bh[tid * 2] = gh[tid * 2];
        bh[tid * 2 + 1] = gh[tid * 2 + 1];
        bl[tid * 2] = gl[tid * 2];
        bl[tid * 2 + 1] = gl[tid * 2 + 1];
    }
    const int wv = tid >> 6;
    const int lane = tid & 63;
    const int l16 = lane & 15;
    const int quad = lane >> 4;
    const int m0 = blockIdx.x * 64 + wv * 16;
    int ra = m0 + l16;
    if (ra >= M) ra = M - 1;
    const float* arow = A + (long)ra * HBLK + quad * 8;

    f32x4 acc[2];
    acc[0] = (f32x4){0.f, 0.f, 0.f, 0.f};
    acc[1] = (f32x4){0.f, 0.f, 0.f, 0.f};
    __syncthreads();

#pragma unroll
    for (int c = 0; c < 4; ++c) {
        const float4 a0 = *(const float4*)(arow + c * 32);
        const float4 a1 = *(const float4*)(arow + c * 32 + 4);
        s8v ah, al;
        split8(a0, a1, ah, al);
#pragma unroll
        for (int j = 0; j < 2; ++j) {
            const s8v whf = *(const s8v*)&lh[((c * 2 + j) * 64 + lane) * 8];
            const s8v wlf = *(const s8v*)&ll[((c * 2 + j) * 64 + lane) * 8];
            acc[j] = __builtin_amdgcn_mfma_f32_16x16x32_bf16(ah, whf, acc[j], 0, 0, 0);
            acc[j] = __builtin_amdgcn_mfma_f32_16x16x32_bf16(ah, wlf, acc[j], 0, 0, 0);
            acc[j] = __builtin_amdgcn_mfma_f32_16x16x32_bf16(al, whf, acc[j], 0, 0, 0);
        }
    }

#pragma unroll
    for (int r = 0; r < 4; ++r) {
        const int gr = m0 + quad * 4 + r;
        if (gr >= M) continue;
#pragma unroll
        for (int j = 0; j < 2; ++j) {
            const int col = j * 16 + l16;
            if (col < OUTD)
                out[(long)gr * OUTD + col] = acc[j][r] + bias[col];
        }
    }
}

// ---------------- fused softmax + weighted gather; one wave per node ----------------
// Fast path (deg <= 64, ~all nodes at avg degree 32): pass 1 computes each edge's
// softmax weight in ONE register per lane (full-wave shfl_xor reductions). Pass 2 is
// a WAVE-UNIFORM loop (all 64 lanes iterate k < ceil(deg/4), idx = 4k+g <= 63 always);
// padding edges contribute exactly w=0, so every __shfl executes with all lanes
// active on well-defined values. Inner loop's only memory op: coalesced 256B zh row.
__global__ void gat_gather(const float* __restrict__ h_in, const float* __restrict__ hs,
                           const _Float16* __restrict__ zh,
                           const float* __restrict__ s_src, const float* __restrict__ s_dst,
                           const int* __restrict__ offs, const int* __restrict__ srcs,
                           float* __restrict__ h_out, int N) {
    const int wave = threadIdx.x >> 6;
    const int lane = threadIdx.x & 63;
    const int n = blockIdx.x * 4 + wave;
    if (n >= N) return;
    const int g = lane >> 4, l = lane & 15;
    const int beg = offs[n], end = offs[n + 1];
    const int deg = end - beg;

    float acc[8] = {};
    if (deg > 0) {
        const float sd = s_dst[n];
        if (deg <= 64) {
            // ---- pass 1: one edge per lane, weight kept in-register ----
            const int sA = srcs[beg + min(lane, deg - 1)];
            float e = sd + s_src[sA];
            e = e > 0.f ? e : 0.01f * e;
            if (lane >= deg) e = -INFINITY;
            float mv = e;
#pragma unroll
            for (int off = 32; off; off >>= 1) mv = fmaxf(mv, __shfl_xor(mv, off));
            const float ex = (lane < deg) ? __expf(e - mv) : 0.f;
            float sv = ex;
#pragma unroll
            for (int off = 32; off; off >>= 1) sv += __shfl_xor(sv, off);
            const float w = ex / fmaxf(sv, 1e-16f);   // exactly 0 for lane >= deg

            // ---- pass 2: uniform trip count; group g handles idx = 4k+g ----
            const int nK = (deg + 3) >> 2;            // wave-uniform
            int k = 0;
            for (; k + 1 < nK; k += 2) {
                const int i0 = 4 * k + g;             // <= 4*nK-1 <= 63
                const int i1 = i0 + 4;
                const int s0 = __shfl(sA, i0);
                const int s1 = __shfl(sA, i1);
                const float w0 = __shfl(w, i0);
                const float w1 = __shfl(w, i1);
                const h8f z0 = *(const h8f*)(zh + (long)s0 * HBLK + 8 * l);
                const h8f z1 = *(const h8f*)(zh + (long)s1 * HBLK + 8 * l);
#pragma unroll
                for (int e2 = 0; e2 < 8; ++e2)
                    acc[e2] += w0 * (float)z0[e2] + w1 * (float)z1[e2];
            }
            if (k < nK) {
                const int i0 = 4 * k + g;
                const int s0 = __shfl(sA, i0);
                const float w0 = __shfl(w, i0);
                const h8f z0 = *(const h8f*)(zh + (long)s0 * HBLK + 8 * l);
#pragma unroll
                for (int e2 = 0; e2 < 8; ++e2)
                    acc[e2] += w0 * (float)z0[e2];
            }
        } else {
            // ---- slow path (deg > 64, rare): recompute weights ----
            float m = -INFINITY, s = 0.f;
            for (int i = beg + lane; i < end; i += 64) {
                float e = sd + s_src[srcs[i]];
                e = e > 0.f ? e : 0.01f * e;
                float nm = fmaxf(m, e);
                s = s * __expf(m - nm) + __expf(e - nm);
                m = nm;
            }
#pragma unroll
            for (int off = 32; off > 0; off >>= 1) {
                float m2 = __shfl_down(m, off);
                float s2 = __shfl_down(s, off);
                if (m2 > m) {
                    float t = m; m = m2; m2 = t;
                    float ts = s; s = s2; s2 = ts;
                }
                s = (m == -INFINITY) ? 0.f : s + s2 * __expf(m2 - m);
            }
            m = __shfl(m, 0);
            s = __shfl(s, 0);
            const float inv = 1.f / fmaxf(s, 1e-16f);
            for (int i = beg + g; i < end; i += 4) {
                const int s0 = srcs[i];
                float e0 = sd + s_src[s0];
                e0 = e0 > 0.f ? e0 : 0.01f * e0;
                const float w0 = __expf(e0 - m) * inv;
                const h8f z0 = *(const h8f*)(zh + (long)s0 * HBLK + 8 * l);
#pragma unroll
                for (int e2 = 0; e2 < 8; ++e2)
                    acc[e2] += w0 * (float)z0[e2];
            }
        }
        // combine the 4 groups (same col mapping)
#pragma unroll
        for (int e2 = 0; e2 < 8; ++e2) {
            acc[e2] += __shfl_down(acc[e2], 32);
            acc[e2] += __shfl_down(acc[e2], 16);
        }
    }

    if (g == 0) {
        const long base = (long)n * HBLK + 8 * l;
        const float4 hi0 = *(const float4*)(h_in + base);
        const float4 hi1 = *(const float4*)(h_in + base + 4);
        float o[8];
        if (deg > 0) {
            const float4 hv0 = *(const float4*)(hs + base);
            const float4 hv1 = *(const float4*)(hs + base + 4);
            const float* hip = (const float*)&hi0;
            const float* hvp = (const float*)&hv0;
#pragma unroll
            for (int e = 0; e < 4; ++e) o[e] = hip[e] + hvp[e] + acc[e];
            const float* hip1 = (const float*)&hi1;
            const float* hvp1 = (const float*)&hv1;
#pragma unroll
            for (int e = 0; e < 4; ++e) o[4 + e] = hip1[e] + hvp1[e] + acc[4 + e];
        } else {  // DGL leaves h at h_in; residual doubles it
            const float* hip = (const float*)&hi0;
            const float* hip1 = (const float*)&hi1;
#pragma unroll
            for (int e = 0; e < 4; ++e) o[e] = 2.f * hip[e];
#pragma unroll
            for (int e = 0; e < 4; ++e) o[4 + e] = 2.f * hip1[e];
        }
        *(float4*)(h_out + base) = *(float4*)&o[0];
        *(float4*)(h_out + base + 4) = *(float4*)&o[4];
    }
}

extern "C" void kernel_launch(void* const* d_in, const int* in_sizes, int n_in,
                              void* d_out, int out_size, void* d_ws, size_t ws_size,
                              hipStream_t stream) {
    const float* feats = (const float*)d_in[0];
    const float* maps  = (const float*)d_in[2];
    const int* src = (const int*)d_in[4];
    const int* dst = (const int*)d_in[5];
    const float* W_eh  = (const float*)d_in[6];
    const float* b_eh  = (const float*)d_in[7];
    const float* W_cat = (const float*)d_in[10];
    const float* b_cat = (const float*)d_in[11];
    const float* Ws1 = (const float*)d_in[12];
    const float* Wf1 = (const float*)d_in[13];
    const float* a1  = (const float*)d_in[14];
    const float* Ws2 = (const float*)d_in[15];
    const float* Wf2 = (const float*)d_in[16];
    const float* a2  = (const float*)d_in[17];
    const float* W_out = (const float*)d_in[18];
    const float* b_out = (const float*)d_in[19];

    const int N = in_sizes[3];            // snorm_n is (N,1)
    const int E = in_sizes[4];
    const int IN_DIM = in_sizes[0] / N;   // 24
    const int MAPD = in_sizes[2] / N;     // 512
    const int OUTD = in_sizes[19];        // 24
    const int KCAT = MAPD + HBLK;         // 640 = W_cat leading dim
    const int KC = (MAPD + IN_DIM + 31) & ~31;  // 544: folded concat K, chunk-padded

    // ---- workspace layout ----
    char* p = (char*)d_ws;
    const size_t NH = (size_t)N * HBLK;
    float* hin  = (float*)p;  p += NH * 4;
    float* hs   = (float*)p;  p += NH * 4;
    float* hout = (float*)p;  p += NH * 4;
    _Float16* zh = (_Float16*)p; p += NH * 2;
    float* ssrc = (float*)p;  p += (size_t)N * 4;
    float* sdst = (float*)p;  p += (size_t)N * 4;
    int* offs   = (int*)p;    p += (size_t)(N + 1) * 4;
    int* srcs   = (int*)p;    p += (size_t)E * 4;   // src payload, dst-sorted
    int* bsums  = (int*)p;    p += 256 * 4;
    int* histT  = (int*)p;    p += (size_t)256 * 256 * 4;  // [bucket][block] scanned counts
    float* bcomb = (float*)p; p += (size_t)HBLK * 4;
    p = (char*)(((uintptr_t)p + 15) & ~(uintptr_t)15);
    int* ebuf = (int*)p;      p += (size_t)E * 4;   // coarse-binned packed (src<<7)|local
    short* Wcat_h = (short*)p; p += (size_t)HBLK * KC * 2;
    short* Wcat_l = (short*)p; p += (size_t)HBLK * KC * 2;
    short* Wout_h = (short*)p; p += (size_t)32 * HBLK * 2;
    short* Wout_l = (short*)p; p += (size_t)32 * HBLK * 2;
    short* Wly_h = (short*)p;  p += (size_t)4 * HBLK * HBLK * 2;  // 4 matrices, 16384 shorts each
    short* Wly_l = (short*)p;  p += (size_t)4 * HBLK * HBLK * 2;

    // ---- CSR by dst: 2-level binning sort (no global atomics) ----
    const int NB1 = (E + EPB - 1) / EPB;       // binning blocks (<=256 for E<=1M)
    const int NBUCK = (N + 127) >> 7;          // 128-node buckets (<=256 for N<=32768)
    const int nHist = 256 * NB1;
    bin_hist<<<NB1, 256, 0, stream>>>(dst, histT, E, NB1);
    scan1<<<NB1, 256, 0, stream>>>(histT, histT, bsums, nHist);
    scan2<<<1, 256, 0, stream>>>(bsums, NB1);
    bin_scatter<<<NB1, 256, 0, stream>>>(src, dst, histT, bsums, ebuf, E, NB1);
    bucket_sort<<<NBUCK, 256, 0, stream>>>(ebuf, histT, bsums, offs, srcs, N, E, NB1);

    // ---- weight fold + split+pack (2 launches) ----
    pack_wcat<<<(HBLK * KC + HBLK + 255) / 256, 256, 0, stream>>>(
        W_cat, KCAT, MAPD, W_eh, IN_DIM, b_eh, b_cat, Wcat_h, Wcat_l, bcomb, KC);
    split_w_packA<<<dim3(64, 5), 256, 0, stream>>>(
        Ws1, Wf1, Ws2, Wf2, W_out, OUTD, Wly_h, Wly_l, Wout_h, Wout_l);

    const int gGrid = (N + 63) / 64;
    const int n4 = (N + 3) / 4;

    // ---- concat GEMM (front GEMM folded in): hin = relu(maps@Wc1^T + feats@Wcomb^T + bcomb)
    gemm_bigk<<<gGrid, 256, 0, stream>>>(
        maps, MAPD, MAPD, feats, IN_DIM, MAPD + IN_DIM, KC,
        Wcat_h, Wcat_l, bcomb, hin, N);

    // ---- GAT layer 1 ----
    gemm_smallk<<<dim3(gGrid, 2), 256, 0, stream>>>(
        hin, Wly_h, Wly_l, Wly_h + 16384, Wly_l + 16384,
        hs, zh, a1, ssrc, sdst, N);
    gat_gather<<<n4, 256, 0, stream>>>(hin, hs, zh, ssrc, sdst, offs, srcs, hout, N);

    // ---- GAT layer 2 ----
    gemm_smallk<<<dim3(gGrid, 2), 256, 0, stream>>>(
        hout, Wly_h + 32768, Wly_l + 32768, Wly_h + 49152, Wly_l + 49152,
        hs, zh, a2, ssrc, sdst, N);
    gat_gather<<<n4, 256, 0, stream>>>(hout, hs, zh, ssrc, sdst, offs, srcs, hin, N);

    // ---- output projection ----
    gemm_out<<<gGrid, 256, 0, stream>>>(hin, Wout_h, Wout_l, b_out, (float*)d_out, N, OUTD);
}